// Round 4
// baseline (4512.295 us; speedup 1.0000x reference)
//
#include <hip/hip_runtime.h>
#include <cstddef>
#include <cmath>

namespace {

constexpr int H = 4, D = 32, HID = 128;
constexpr int NA = 100000, NW = 20000, NO = 50000;
constexpr int NTOT = NA + NW + NO;
constexpr int E = 150000;
constexpr float SCALE = 0.17677669529663687f;  // 1/sqrt(32)

__device__ __forceinline__ float gelu_exact(float x) {
  return 0.5f * x * (1.f + erff(x * 0.7071067811865475f));
}

__device__ __forceinline__ unsigned short f2bf(float f) {  // RNE
  unsigned u = __float_as_uint(f);
  return (unsigned short)((u + 0x7FFF + ((u >> 16) & 1)) >> 16);
}
__device__ __forceinline__ float bf2f(unsigned short s) {
  return __uint_as_float(((unsigned)s) << 16);
}
__device__ __forceinline__ unsigned pack2(float lo, float hi) {
  return (unsigned)f2bf(lo) | ((unsigned)f2bf(hi) << 16);
}

// load 32 contiguous bf16 (as ushort) -> 32 floats; p must be 16B-aligned
__device__ __forceinline__ void load32bf(const unsigned short* p, float* out) {
  const uint4* u4 = (const uint4*)p;
  #pragma unroll
  for (int i = 0; i < 4; i++) {
    uint4 u = u4[i];
    unsigned w[4] = {u.x, u.y, u.z, u.w};
    #pragma unroll
    for (int j = 0; j < 4; j++) {
      out[i * 8 + j * 2 + 0] = __uint_as_float(w[j] << 16);
      out[i * 8 + j * 2 + 1] = __uint_as_float(w[j] & 0xFFFF0000u);
    }
  }
}

// ---------------- GEMM (fp32 compute) ----------------
template <bool RELU_OUT, bool OUT_BF16>
__global__ __launch_bounds__(256) void gemm_tiled(
    const float* __restrict__ A, const float* __restrict__ W,
    const float* __restrict__ bias, void* __restrict__ Cv,
    int M, int K, int ldw, int ldc) {
  __shared__ float As[32][68];
  __shared__ float Bs[32][68];
  const int tid = threadIdx.x;
  const int bm = blockIdx.x * 64;
  const int bn = blockIdx.y * 64;
  const int tx = tid & 15;
  const int ty = tid >> 4;
  float acc[4][4] = {};
  for (int kk = 0; kk < K; kk += 32) {
    #pragma unroll
    for (int i = 0; i < 8; i++) {
      int idx = tid + i * 256;
      int c = idx & 31, r = idx >> 5;
      int gr = bm + r;
      float v = 0.f;
      if (gr < M) v = A[(size_t)gr * K + kk + c];
      As[c][r] = v;
    }
    #pragma unroll
    for (int i = 0; i < 8; i++) {
      int idx = tid + i * 256;
      int c = idx & 63, r = idx >> 6;
      Bs[r][c] = W[(size_t)(kk + r) * ldw + bn + c];
    }
    __syncthreads();
    #pragma unroll
    for (int k = 0; k < 32; k++) {
      const float4 a4 = *(const float4*)&As[k][ty * 4];
      const float4 b4 = *(const float4*)&Bs[k][tx * 4];
      float av[4] = {a4.x, a4.y, a4.z, a4.w};
      float bv[4] = {b4.x, b4.y, b4.z, b4.w};
      #pragma unroll
      for (int i = 0; i < 4; i++)
        #pragma unroll
        for (int j = 0; j < 4; j++) acc[i][j] += av[i] * bv[j];
    }
    __syncthreads();
  }
  const float4 bb = *(const float4*)&bias[bn + tx * 4];
  float bv[4] = {bb.x, bb.y, bb.z, bb.w};
  #pragma unroll
  for (int i = 0; i < 4; i++) {
    int gr = bm + ty * 4 + i;
    if (gr >= M) continue;
    float o[4];
    #pragma unroll
    for (int j = 0; j < 4; j++) {
      o[j] = acc[i][j] + bv[j];
      if (RELU_OUT) o[j] = fmaxf(o[j], 0.f);
    }
    if (OUT_BF16) {
      ushort4 s;
      s.x = f2bf(o[0]); s.y = f2bf(o[1]); s.z = f2bf(o[2]); s.w = f2bf(o[3]);
      *(ushort4*)&((unsigned short*)Cv)[(size_t)gr * ldc + bn + tx * 4] = s;
    } else {
      float4 v;
      v.x = o[0]; v.y = o[1]; v.z = o[2]; v.w = o[3];
      *(float4*)&((float*)Cv)[(size_t)gr * ldc + bn + tx * 4] = v;
    }
  }
}

// fused: xs = relu(LN( g*(gelu(A_bf16) @ W_o + b_o) + (1-g)*xs ))
__global__ __launch_bounds__(256) void gemm_wo_ln(
    const unsigned short* __restrict__ A, const float* __restrict__ W,
    const float* __restrict__ bias, float* __restrict__ xs,
    const float* __restrict__ skip_p, const float* __restrict__ g_ln,
    const float* __restrict__ b_ln, int M) {
  __shared__ float As[32][68];
  __shared__ float Bs[32][132];
  const int tid = threadIdx.x;
  const int bm = blockIdx.x * 64;
  const int tx = tid & 15;   // 8 cols each
  const int ty = tid >> 4;   // 4 rows each
  float acc[4][8] = {};
  for (int kk = 0; kk < HID; kk += 32) {
    #pragma unroll
    for (int i = 0; i < 8; i++) {
      int idx = tid + i * 256;
      int c = idx & 31, r = idx >> 5;
      int gr = bm + r;
      float v = 0.f;
      if (gr < M) v = gelu_exact(bf2f(A[(size_t)gr * HID + kk + c]));
      As[c][r] = v;
    }
    #pragma unroll
    for (int i = 0; i < 16; i++) {
      int idx = tid + i * 256;
      int c = idx & 127, r = idx >> 7;
      Bs[r][c] = W[(size_t)(kk + r) * HID + c];
    }
    __syncthreads();
    #pragma unroll
    for (int k = 0; k < 32; k++) {
      const float4 a4 = *(const float4*)&As[k][ty * 4];
      const float4 b0 = *(const float4*)&Bs[k][tx * 8];
      const float4 b1 = *(const float4*)&Bs[k][tx * 8 + 4];
      float av[4] = {a4.x, a4.y, a4.z, a4.w};
      float bv[8] = {b0.x, b0.y, b0.z, b0.w, b1.x, b1.y, b1.z, b1.w};
      #pragma unroll
      for (int i = 0; i < 4; i++)
        #pragma unroll
        for (int j = 0; j < 8; j++) acc[i][j] += av[i] * bv[j];
    }
    __syncthreads();
  }
  const float g = 1.f / (1.f + expf(-skip_p[0]));
  float bb[8], gl[8], bl[8];
  #pragma unroll
  for (int j = 0; j < 8; j++) {
    bb[j] = bias[tx * 8 + j];
    gl[j] = g_ln[tx * 8 + j];
    bl[j] = b_ln[tx * 8 + j];
  }
  #pragma unroll
  for (int i = 0; i < 4; i++) {
    int gr = bm + ty * 4 + i;
    bool ok = gr < M;
    float xold[8] = {};
    if (ok) {
      const float4 x0 = *(const float4*)&xs[(size_t)gr * HID + tx * 8];
      const float4 x1 = *(const float4*)&xs[(size_t)gr * HID + tx * 8 + 4];
      xold[0] = x0.x; xold[1] = x0.y; xold[2] = x0.z; xold[3] = x0.w;
      xold[4] = x1.x; xold[5] = x1.y; xold[6] = x1.z; xold[7] = x1.w;
    }
    float v[8];
    float sum = 0.f, sq = 0.f;
    #pragma unroll
    for (int j = 0; j < 8; j++) {
      v[j] = g * (acc[i][j] + bb[j]) + (1.f - g) * xold[j];
      sum += v[j];
      sq += v[j] * v[j];
    }
    #pragma unroll
    for (int m = 1; m < 16; m <<= 1) {
      sum += __shfl_xor(sum, m, 64);
      sq += __shfl_xor(sq, m, 64);
    }
    float mu = sum * (1.f / 128.f);
    float var = sq * (1.f / 128.f) - mu * mu;
    float r = rsqrtf(var + 1e-5f);
    if (ok) {
      float y[8];
      #pragma unroll
      for (int j = 0; j < 8; j++)
        y[j] = fmaxf((v[j] - mu) * r * gl[j] + bl[j], 0.f);
      float4 o0, o1;
      o0.x = y[0]; o0.y = y[1]; o0.z = y[2]; o0.w = y[3];
      o1.x = y[4]; o1.y = y[5]; o1.z = y[6]; o1.w = y[7];
      *(float4*)&xs[(size_t)gr * HID + tx * 8] = o0;
      *(float4*)&xs[(size_t)gr * HID + tx * 8 + 4] = o1;
    }
  }
}

// ---------------- CSR build (deterministic) ----------------
__global__ __launch_bounds__(256) void csr_hist(const int* __restrict__ dst,
                                                int* __restrict__ cnt, int n) {
  int e = blockIdx.x * 256 + threadIdx.x;
  if (e < n) atomicAdd(&cnt[dst[e]], 1);
}

__global__ __launch_bounds__(256) void scan_block(const int* __restrict__ cnt,
                                                  int* __restrict__ excl,
                                                  int* __restrict__ bsum,
                                                  int n) {
  __shared__ int tmp[256];
  int i = blockIdx.x * 256 + threadIdx.x;
  int v = (i < n) ? cnt[i] : 0;
  tmp[threadIdx.x] = v;
  __syncthreads();
  int acc = v;
  for (int off = 1; off < 256; off <<= 1) {
    int other = (threadIdx.x >= off) ? tmp[threadIdx.x - off] : 0;
    __syncthreads();
    acc += other;
    tmp[threadIdx.x] = acc;
    __syncthreads();
  }
  if (i < n) excl[i] = acc - v;
  if (threadIdx.x == 255) bsum[blockIdx.x] = acc;
}

__global__ __launch_bounds__(256) void scan_bsums(int* __restrict__ bsum,
                                                  int nb) {
  __shared__ int tmp[256];
  __shared__ int carry;
  if (threadIdx.x == 0) carry = 0;
  __syncthreads();
  for (int start = 0; start < nb; start += 256) {
    int i = start + threadIdx.x;
    int v = (i < nb) ? bsum[i] : 0;
    tmp[threadIdx.x] = v;
    __syncthreads();
    int acc = v;
    for (int off = 1; off < 256; off <<= 1) {
      int other = (threadIdx.x >= off) ? tmp[threadIdx.x - off] : 0;
      __syncthreads();
      acc += other;
      tmp[threadIdx.x] = acc;
      __syncthreads();
    }
    int c = carry;
    if (i < nb) bsum[i] = c + acc - v;
    __syncthreads();
    if (threadIdx.x == 255) carry = c + acc;
    __syncthreads();
  }
}

__global__ __launch_bounds__(256) void csr_finalize(int* __restrict__ rp,
                                                    const int* __restrict__ bsum,
                                                    int* __restrict__ cursor,
                                                    int n, int ne) {
  int i = blockIdx.x * 256 + threadIdx.x;
  if (i < n) {
    int v = rp[i] + bsum[i >> 8];
    rp[i] = v;
    cursor[i] = v;
  } else if (i == n) {
    rp[n] = ne;
  }
}

__global__ __launch_bounds__(256) void csr_scatter(const int* __restrict__ dst,
                                                   int* __restrict__ cursor,
                                                   int* __restrict__ ce, int n) {
  int e = blockIdx.x * 256 + threadIdx.x;
  if (e < n) {
    int slot = atomicAdd(&cursor[dst[e]], 1);
    ce[slot] = e;
  }
}

__global__ __launch_bounds__(256) void csr_sort(const int* __restrict__ rp,
                                                int* __restrict__ ce, int n) {
  int d = blockIdx.x * 256 + threadIdx.x;
  if (d >= n) return;
  int b = rp[d], e = rp[d + 1];
  for (int i = b + 1; i < e; i++) {
    int key = ce[i];
    int j = i - 1;
    while (j >= b && ce[j] > key) { ce[j + 1] = ce[j]; j--; }
    ce[j + 1] = key;
  }
}

// ---------------- attention ----------------
// slot-parallel: thread = (csr slot i, h).
// alpha[i,h] = k[src] . (A[h] @ q[dst]) * p[h] * scale   (written slot-ordered)
__global__ __launch_bounds__(256) void alpha_edge(
    const unsigned short* __restrict__ kbuf,
    const unsigned short* __restrict__ qbuf, const int* __restrict__ ce,
    const int* __restrict__ src, const int* __restrict__ dst,
    const float* __restrict__ A, const float* __restrict__ prel,
    float* __restrict__ alphaOut, int srcOff, int dstOff) {
  int t = blockIdx.x * 256 + threadIdx.x;
  if (t >= E * H) return;
  int i = t >> 2, h = t & 3;
  int e = ce[i];
  int s_ = src[e], d_ = dst[e];
  float qv[32];
  load32bf(qbuf + (size_t)(dstOff + d_) * HID + h * 32, qv);
  const float* Ar = A + h * D * D;
  float qA[32];
  #pragma unroll 4
  for (int d2 = 0; d2 < 32; d2++) {
    const float4* r4 = (const float4*)(Ar + d2 * 32);
    float a = 0.f;
    #pragma unroll
    for (int j = 0; j < 8; j++) {
      float4 w = r4[j];
      a += w.x * qv[j * 4] + w.y * qv[j * 4 + 1] + w.z * qv[j * 4 + 2] +
           w.w * qv[j * 4 + 3];
    }
    qA[d2] = a;
  }
  float kk[32];
  load32bf(kbuf + (size_t)(srcOff + s_) * HID + h * 32, kk);
  float a = 0.f;
  #pragma unroll
  for (int j = 0; j < 32; j++) a += qA[j] * kk[j];
  a *= prel[h] * SCALE;
  alphaOut[(size_t)i * H + h] = a;
}

// thread = (dstLocal, h). Fused: m/den from slot-ordered alpha (contiguous),
// then sv = sum_e exp(alpha-m)*v_src ; agg = (sum_et sv@M)/den  -> bf16
__global__ __launch_bounds__(256) void agg_gather(
    const unsigned short* __restrict__ vbuf, const int* __restrict__ rp0,
    const int* __restrict__ ce0, const int* __restrict__ src0,
    const float* __restrict__ M0, const float* __restrict__ alpha0,
    const int* __restrict__ rp1, const int* __restrict__ ce1,
    const int* __restrict__ src1, const float* __restrict__ M1,
    const float* __restrict__ alpha1, int net, int srcOff0, int srcOff1,
    int dstOff, int Ndst, unsigned short* __restrict__ agg) {
  int t = blockIdx.x * 256 + threadIdx.x;
  if (t >= Ndst * H) return;
  int dl = t >> 2, h = t & 3;
  // pass 1: max over all this dst's slots (contiguous alpha reads)
  float mx = -INFINITY;
  for (int s = 0; s < net; s++) {
    const int* rp = s ? rp1 : rp0;
    const float* al = s ? alpha1 : alpha0;
    int b = rp[dl], en = rp[dl + 1];
    for (int i = b; i < en; i++) mx = fmaxf(mx, al[(size_t)i * H + h]);
  }
  // pass 2: den + weighted v gather + per-et M transform
  float den = 0.f;
  float acc[32] = {};
  for (int s = 0; s < net; s++) {
    const int* rp = s ? rp1 : rp0;
    const int* ce = s ? ce1 : ce0;
    const int* src = s ? src1 : src0;
    const float* Mm = (s ? M1 : M0) + h * D * D;
    const float* al = s ? alpha1 : alpha0;
    int srcOff = s ? srcOff1 : srcOff0;
    int b = rp[dl], en = rp[dl + 1];
    if (b == en) continue;  // skip M transform for empty per-et lists
    float sv[32] = {};
    #pragma unroll 2
    for (int i = b; i < en; i++) {
      float w = expf(al[(size_t)i * H + h] - mx);
      den += w;
      int e = ce[i];
      float vv[32];
      load32bf(vbuf + (size_t)(srcOff + src[e]) * HID + h * 32, vv);
      #pragma unroll
      for (int j = 0; j < 32; j++) sv[j] += w * vv[j];
    }
    #pragma unroll 4
    for (int d2 = 0; d2 < 32; d2++) {
      float sd = sv[d2];
      const float4* r4 = (const float4*)(Mm + d2 * 32);
      #pragma unroll
      for (int j = 0; j < 8; j++) {
        float4 w = r4[j];
        acc[j * 4 + 0] += sd * w.x; acc[j * 4 + 1] += sd * w.y;
        acc[j * 4 + 2] += sd * w.z; acc[j * 4 + 3] += sd * w.w;
      }
    }
  }
  float inv = 1.f / (den + 1e-16f);
  unsigned short* out = agg + (size_t)(dstOff + dl) * HID + h * 32;
  #pragma unroll
  for (int i = 0; i < 4; i++) {
    uint4 w;
    w.x = pack2(acc[i * 8 + 0] * inv, acc[i * 8 + 1] * inv);
    w.y = pack2(acc[i * 8 + 2] * inv, acc[i * 8 + 3] * inv);
    w.z = pack2(acc[i * 8 + 4] * inv, acc[i * 8 + 5] * inv);
    w.w = pack2(acc[i * 8 + 6] * inv, acc[i * 8 + 7] * inv);
    *(uint4*)(out + i * 8) = w;
  }
}

__global__ __launch_bounds__(256) void head_kernel(
    const float* __restrict__ xs0, const float* __restrict__ w_head,
    const float* __restrict__ b_head, const float* __restrict__ basep,
    float* __restrict__ out, int Nrows) {
  int wid = (blockIdx.x * 256 + threadIdx.x) >> 6;
  int lane = threadIdx.x & 63;
  if (wid >= Nrows) return;
  size_t base = (size_t)wid * HID;
  float d = xs0[base + lane] * w_head[lane] +
            xs0[base + 64 + lane] * w_head[64 + lane];
  #pragma unroll
  for (int m = 1; m < 64; m <<= 1) d += __shfl_xor(d, m, 64);
  if (lane == 0) out[wid] = basep[0] + b_head[0] + d;
}

}  // namespace

extern "C" void kernel_launch(void* const* d_in, const int* in_sizes, int n_in,
                              void* d_out, int out_size, void* d_ws,
                              size_t ws_size, hipStream_t stream) {
  const float* x_a = (const float*)d_in[0];
  const float* x_w = (const float*)d_in[1];
  const float* x_o = (const float*)d_in[2];
  const float* W_in = (const float*)d_in[3];
  const float* b_in = (const float*)d_in[4];
  const float* W_kqv = (const float*)d_in[5];
  const float* b_kqv = (const float*)d_in[6];
  const float* a_rel = (const float*)d_in[7];
  const float* m_rel = (const float*)d_in[8];
  const float* p_rel = (const float*)d_in[9];
  const float* skip_p = (const float*)d_in[10];
  const float* W_o = (const float*)d_in[11];
  const float* b_o = (const float*)d_in[12];
  const float* ln_g = (const float*)d_in[13];
  const float* ln_b = (const float*)d_in[14];
  const float* w_head = (const float*)d_in[15];
  const float* b_head = (const float*)d_in[16];
  const float* basep = (const float*)d_in[17];
  const int* srcs[4] = {(const int*)d_in[18], (const int*)d_in[20],
                        (const int*)d_in[22], (const int*)d_in[24]};
  const int* dsts[4] = {(const int*)d_in[19], (const int*)d_in[21],
                        (const int*)d_in[23], (const int*)d_in[25]};
  const int OFF[4] = {0, NA, NA + NW, NTOT};
  const int NT[3] = {NA, NW, NO};
  const float* xin[3] = {x_a, x_w, x_o};

  // ---- workspace layout (~188 MB) ----
  const size_t SZ_XS = (size_t)NTOT * HID * 4;   // fp32 xs
  const size_t SZ_KV = (size_t)NTOT * HID * 2;   // bf16 k -> v
  const size_t SZ_QA = (size_t)NTOT * HID * 2;   // bf16 q -> agg
  const size_t SZ_AL = (size_t)4 * E * H * 4;    // fp32 slot-ordered alpha
  const int RP_TOT = 2 * (NA + 1) + (NW + 1) + (NO + 1);
  const size_t SZ_RP = ((size_t)RP_TOT * 4 + 63) & ~63ull;
  const size_t SZ_CE = (size_t)4 * E * 4;
  const size_t SZ_CU = ((size_t)(NA + 1) * 4 + 63) & ~63ull;
  const size_t SZ_BS = 512 * 4;
  const size_t need =
      SZ_XS + SZ_KV + SZ_QA + SZ_AL + SZ_RP + SZ_CE + 2 * SZ_CU + SZ_BS;
  if (ws_size < need) return;

  char* p = (char*)d_ws;
  float* xs = (float*)p;                     p += SZ_XS;
  unsigned short* kv = (unsigned short*)p;   p += SZ_KV;
  unsigned short* qagg = (unsigned short*)p; p += SZ_QA;
  float* alphaB = (float*)p;                 p += SZ_AL;
  int* rpAll = (int*)p;                      p += SZ_RP;
  int* ceAll = (int*)p;                      p += SZ_CE;
  int* cursor = (int*)p;                     p += SZ_CU;
  int* cnt = (int*)p;                        p += SZ_CU;
  int* bsum = (int*)p;

  const int rpOff[4] = {0, NA + 1, 2 * (NA + 1), 2 * (NA + 1) + NW + 1};
  const int NdstE[4] = {NA, NA, NW, NO};
  const int srcOffE[4] = {OFF[1], OFF[2], 0, 0};
  const int dstOffE[4] = {0, 0, OFF[1], OFF[2]};
  const int eb = (E + 255) / 256;
  const int ebh = (E * H + 255) / 256;

  // ---- CSR build (once; edges shared by both layers) ----
  for (int et = 0; et < 4; et++) {
    int nd = NdstE[et];
    int* rp = rpAll + rpOff[et];
    int* ce = ceAll + (size_t)et * E;
    hipMemsetAsync(cnt, 0, (size_t)nd * 4, stream);
    csr_hist<<<eb, 256, 0, stream>>>(dsts[et], cnt, E);
    int nb = (nd + 255) / 256;
    scan_block<<<nb, 256, 0, stream>>>(cnt, rp, bsum, nd);
    scan_bsums<<<1, 256, 0, stream>>>(bsum, nb);
    csr_finalize<<<(nd + 256) / 256 + 1, 256, 0, stream>>>(rp, bsum, cursor,
                                                           nd, E);
    csr_scatter<<<eb, 256, 0, stream>>>(dsts[et], cursor, ce, E);
    csr_sort<<<(nd + 255) / 256, 256, 0, stream>>>(rp, ce, nd);
  }

  // ---- input projection: xs[t] = relu(x @ W_in[t] + b_in[t]) ----
  for (int t = 0; t < 3; t++) {
    dim3 g((NT[t] + 63) / 64, 2);
    gemm_tiled<true, false><<<g, 256, 0, stream>>>(
        xin[t], W_in + (size_t)t * 64 * HID, b_in + t * HID,
        xs + (size_t)OFF[t] * HID, NT[t], 64, HID, HID);
  }

  for (int l = 0; l < 2; l++) {
    const size_t DD = (size_t)H * D * D;
    // k -> kv (bf16), q -> qagg (bf16)
    for (int t = 0; t < 3; t++) {
      const float* Wk = W_kqv + (size_t)(l * 3 + t) * HID * 3 * HID;
      const float* bk = b_kqv + (size_t)(l * 3 + t) * 3 * HID;
      dim3 g((NT[t] + 63) / 64, 2);
      gemm_tiled<false, true><<<g, 256, 0, stream>>>(
          xs + (size_t)OFF[t] * HID, Wk, bk, kv + (size_t)OFF[t] * HID, NT[t],
          HID, 3 * HID, HID);
      gemm_tiled<false, true><<<g, 256, 0, stream>>>(
          xs + (size_t)OFF[t] * HID, Wk + HID, bk + HID,
          qagg + (size_t)OFF[t] * HID, NT[t], HID, 3 * HID, HID);
    }
    // slot-parallel alpha, one launch per edge type
    const float* Al = a_rel + (size_t)l * 4 * DD;
    const float* Ml = m_rel + (size_t)l * 4 * DD;
    const float* Pl = p_rel + (size_t)l * 4 * H;
    for (int et = 0; et < 4; et++)
      alpha_edge<<<ebh, 256, 0, stream>>>(
          kv, qagg, ceAll + (size_t)et * E, srcs[et], dsts[et], Al + et * DD,
          Pl + et * H, alphaB + (size_t)et * E * H, srcOffE[et], dstOffE[et]);
    // v -> kv (bf16), overwriting k (dead after alpha)
    for (int t = 0; t < 3; t++) {
      const float* Wk = W_kqv + (size_t)(l * 3 + t) * HID * 3 * HID;
      const float* bk = b_kqv + (size_t)(l * 3 + t) * 3 * HID;
      dim3 g((NT[t] + 63) / 64, 2);
      gemm_tiled<false, true><<<g, 256, 0, stream>>>(
          xs + (size_t)OFF[t] * HID, Wk + 2 * HID, bk + 2 * HID,
          kv + (size_t)OFF[t] * HID, NT[t], HID, 3 * HID, HID);
    }
    // fused max/den + agg gather -> qagg (bf16), overwriting q
    agg_gather<<<(NA * H + 255) / 256, 256, 0, stream>>>(
        kv, rpAll + rpOff[0], ceAll, srcs[0], Ml, alphaB, rpAll + rpOff[1],
        ceAll + E, srcs[1], Ml + DD, alphaB + (size_t)E * H, 2, srcOffE[0],
        srcOffE[1], 0, NA, qagg);
    agg_gather<<<(NW * H + 255) / 256, 256, 0, stream>>>(
        kv, rpAll + rpOff[2], ceAll + 2 * (size_t)E, srcs[2], Ml + 2 * DD,
        alphaB + 2 * (size_t)E * H, nullptr, nullptr, nullptr, nullptr, nullptr,
        1, srcOffE[2], 0, OFF[1], NW, qagg);
    agg_gather<<<(NO * H + 255) / 256, 256, 0, stream>>>(
        kv, rpAll + rpOff[3], ceAll + 3 * (size_t)E, srcs[3], Ml + 3 * DD,
        alphaB + 3 * (size_t)E * H, nullptr, nullptr, nullptr, nullptr, nullptr,
        1, srcOffE[3], 0, OFF[2], NO, qagg);
    // fused: xs = relu(LN(g*(gelu(agg) @ W_o + b_o) + (1-g)*xs))
    for (int t = 0; t < 3; t++) {
      int blocks = (NT[t] + 63) / 64;
      gemm_wo_ln<<<blocks, 256, 0, stream>>>(
          qagg + (size_t)OFF[t] * HID, W_o + (size_t)(l * 3 + t) * HID * HID,
          b_o + (size_t)(l * 3 + t) * HID, xs + (size_t)OFF[t] * HID,
          skip_p + l * 3 + t, ln_g + (size_t)(l * 3 + t) * HID,
          ln_b + (size_t)(l * 3 + t) * HID, NT[t]);
    }
  }
  head_kernel<<<(NA + 3) / 4, 256, 0, stream>>>(xs, w_head, b_head, basep,
                                                (float*)d_out, NA);
}

// Round 5
// 4045.950 us; speedup vs baseline: 1.1153x; 1.1153x over previous
//
#include <hip/hip_runtime.h>
#include <cstddef>
#include <cmath>

namespace {

constexpr int H = 4, D = 32, HID = 128;
constexpr int NA = 100000, NW = 20000, NO = 50000;
constexpr int NTOT = NA + NW + NO;
constexpr int E = 150000;
constexpr float SCALE = 0.17677669529663687f;  // 1/sqrt(32)

__device__ __forceinline__ float gelu_exact(float x) {
  return 0.5f * x * (1.f + erff(x * 0.7071067811865475f));
}

__device__ __forceinline__ unsigned short f2bf(float f) {  // RNE
  unsigned u = __float_as_uint(f);
  return (unsigned short)((u + 0x7FFF + ((u >> 16) & 1)) >> 16);
}
__device__ __forceinline__ float bf2f(unsigned short s) {
  return __uint_as_float(((unsigned)s) << 16);
}

// load 32 contiguous bf16 (as ushort) -> 32 floats; p must be 16B-aligned
__device__ __forceinline__ void load32bf(const unsigned short* p, float* out) {
  const uint4* u4 = (const uint4*)p;
  #pragma unroll
  for (int i = 0; i < 4; i++) {
    uint4 u = u4[i];
    unsigned w[4] = {u.x, u.y, u.z, u.w};
    #pragma unroll
    for (int j = 0; j < 4; j++) {
      out[i * 8 + j * 2 + 0] = __uint_as_float(w[j] << 16);
      out[i * 8 + j * 2 + 1] = __uint_as_float(w[j] & 0xFFFF0000u);
    }
  }
}

// ---------------- GEMM (fp32 compute) ----------------
template <bool RELU_OUT, bool OUT_BF16>
__global__ __launch_bounds__(256) void gemm_tiled(
    const float* __restrict__ A, const float* __restrict__ W,
    const float* __restrict__ bias, void* __restrict__ Cv,
    int M, int K, int ldw, int ldc) {
  __shared__ float As[32][68];
  __shared__ float Bs[32][68];
  const int tid = threadIdx.x;
  const int bm = blockIdx.x * 64;
  const int bn = blockIdx.y * 64;
  const int tx = tid & 15;
  const int ty = tid >> 4;
  float acc[4][4] = {};
  for (int kk = 0; kk < K; kk += 32) {
    #pragma unroll
    for (int i = 0; i < 8; i++) {
      int idx = tid + i * 256;
      int c = idx & 31, r = idx >> 5;
      int gr = bm + r;
      float v = 0.f;
      if (gr < M) v = A[(size_t)gr * K + kk + c];
      As[c][r] = v;
    }
    #pragma unroll
    for (int i = 0; i < 8; i++) {
      int idx = tid + i * 256;
      int c = idx & 63, r = idx >> 6;
      Bs[r][c] = W[(size_t)(kk + r) * ldw + bn + c];
    }
    __syncthreads();
    #pragma unroll
    for (int k = 0; k < 32; k++) {
      const float4 a4 = *(const float4*)&As[k][ty * 4];
      const float4 b4 = *(const float4*)&Bs[k][tx * 4];
      float av[4] = {a4.x, a4.y, a4.z, a4.w};
      float bv[4] = {b4.x, b4.y, b4.z, b4.w};
      #pragma unroll
      for (int i = 0; i < 4; i++)
        #pragma unroll
        for (int j = 0; j < 4; j++) acc[i][j] += av[i] * bv[j];
    }
    __syncthreads();
  }
  const float4 bb = *(const float4*)&bias[bn + tx * 4];
  float bv[4] = {bb.x, bb.y, bb.z, bb.w};
  #pragma unroll
  for (int i = 0; i < 4; i++) {
    int gr = bm + ty * 4 + i;
    if (gr >= M) continue;
    float o[4];
    #pragma unroll
    for (int j = 0; j < 4; j++) {
      o[j] = acc[i][j] + bv[j];
      if (RELU_OUT) o[j] = fmaxf(o[j], 0.f);
    }
    if (OUT_BF16) {
      ushort4 s;
      s.x = f2bf(o[0]); s.y = f2bf(o[1]); s.z = f2bf(o[2]); s.w = f2bf(o[3]);
      *(ushort4*)&((unsigned short*)Cv)[(size_t)gr * ldc + bn + tx * 4] = s;
    } else {
      float4 v;
      v.x = o[0]; v.y = o[1]; v.z = o[2]; v.w = o[3];
      *(float4*)&((float*)Cv)[(size_t)gr * ldc + bn + tx * 4] = v;
    }
  }
}

// fused: xs = relu(LN( g*(gelu(A_bf16) @ W_o + b_o) + (1-g)*xs ))
__global__ __launch_bounds__(256) void gemm_wo_ln(
    const unsigned short* __restrict__ A, const float* __restrict__ W,
    const float* __restrict__ bias, float* __restrict__ xs,
    const float* __restrict__ skip_p, const float* __restrict__ g_ln,
    const float* __restrict__ b_ln, int M) {
  __shared__ float As[32][68];
  __shared__ float Bs[32][132];
  const int tid = threadIdx.x;
  const int bm = blockIdx.x * 64;
  const int tx = tid & 15;   // 8 cols each
  const int ty = tid >> 4;   // 4 rows each
  float acc[4][8] = {};
  for (int kk = 0; kk < HID; kk += 32) {
    #pragma unroll
    for (int i = 0; i < 8; i++) {
      int idx = tid + i * 256;
      int c = idx & 31, r = idx >> 5;
      int gr = bm + r;
      float v = 0.f;
      if (gr < M) v = gelu_exact(bf2f(A[(size_t)gr * HID + kk + c]));
      As[c][r] = v;
    }
    #pragma unroll
    for (int i = 0; i < 16; i++) {
      int idx = tid + i * 256;
      int c = idx & 127, r = idx >> 7;
      Bs[r][c] = W[(size_t)(kk + r) * HID + c];
    }
    __syncthreads();
    #pragma unroll
    for (int k = 0; k < 32; k++) {
      const float4 a4 = *(const float4*)&As[k][ty * 4];
      const float4 b0 = *(const float4*)&Bs[k][tx * 8];
      const float4 b1 = *(const float4*)&Bs[k][tx * 8 + 4];
      float av[4] = {a4.x, a4.y, a4.z, a4.w};
      float bv[8] = {b0.x, b0.y, b0.z, b0.w, b1.x, b1.y, b1.z, b1.w};
      #pragma unroll
      for (int i = 0; i < 4; i++)
        #pragma unroll
        for (int j = 0; j < 8; j++) acc[i][j] += av[i] * bv[j];
    }
    __syncthreads();
  }
  const float g = 1.f / (1.f + expf(-skip_p[0]));
  float bb[8], gl[8], bl[8];
  #pragma unroll
  for (int j = 0; j < 8; j++) {
    bb[j] = bias[tx * 8 + j];
    gl[j] = g_ln[tx * 8 + j];
    bl[j] = b_ln[tx * 8 + j];
  }
  #pragma unroll
  for (int i = 0; i < 4; i++) {
    int gr = bm + ty * 4 + i;
    bool ok = gr < M;
    float xold[8] = {};
    if (ok) {
      const float4 x0 = *(const float4*)&xs[(size_t)gr * HID + tx * 8];
      const float4 x1 = *(const float4*)&xs[(size_t)gr * HID + tx * 8 + 4];
      xold[0] = x0.x; xold[1] = x0.y; xold[2] = x0.z; xold[3] = x0.w;
      xold[4] = x1.x; xold[5] = x1.y; xold[6] = x1.z; xold[7] = x1.w;
    }
    float v[8];
    float sum = 0.f, sq = 0.f;
    #pragma unroll
    for (int j = 0; j < 8; j++) {
      v[j] = g * (acc[i][j] + bb[j]) + (1.f - g) * xold[j];
      sum += v[j];
      sq += v[j] * v[j];
    }
    #pragma unroll
    for (int m = 1; m < 16; m <<= 1) {
      sum += __shfl_xor(sum, m, 64);
      sq += __shfl_xor(sq, m, 64);
    }
    float mu = sum * (1.f / 128.f);
    float var = sq * (1.f / 128.f) - mu * mu;
    float r = rsqrtf(var + 1e-5f);
    if (ok) {
      float y[8];
      #pragma unroll
      for (int j = 0; j < 8; j++)
        y[j] = fmaxf((v[j] - mu) * r * gl[j] + bl[j], 0.f);
      float4 o0, o1;
      o0.x = y[0]; o0.y = y[1]; o0.z = y[2]; o0.w = y[3];
      o1.x = y[4]; o1.y = y[5]; o1.z = y[6]; o1.w = y[7];
      *(float4*)&xs[(size_t)gr * HID + tx * 8] = o0;
      *(float4*)&xs[(size_t)gr * HID + tx * 8 + 4] = o1;
    }
  }
}

// ---------------- CSR build (deterministic) ----------------
__global__ __launch_bounds__(256) void csr_hist(const int* __restrict__ dst,
                                                int* __restrict__ cnt, int n) {
  int e = blockIdx.x * 256 + threadIdx.x;
  if (e < n) atomicAdd(&cnt[dst[e]], 1);
}

__global__ __launch_bounds__(256) void scan_block(const int* __restrict__ cnt,
                                                  int* __restrict__ excl,
                                                  int* __restrict__ bsum,
                                                  int n) {
  __shared__ int tmp[256];
  int i = blockIdx.x * 256 + threadIdx.x;
  int v = (i < n) ? cnt[i] : 0;
  tmp[threadIdx.x] = v;
  __syncthreads();
  int acc = v;
  for (int off = 1; off < 256; off <<= 1) {
    int other = (threadIdx.x >= off) ? tmp[threadIdx.x - off] : 0;
    __syncthreads();
    acc += other;
    tmp[threadIdx.x] = acc;
    __syncthreads();
  }
  if (i < n) excl[i] = acc - v;
  if (threadIdx.x == 255) bsum[blockIdx.x] = acc;
}

__global__ __launch_bounds__(256) void scan_bsums(int* __restrict__ bsum,
                                                  int nb) {
  __shared__ int tmp[256];
  __shared__ int carry;
  if (threadIdx.x == 0) carry = 0;
  __syncthreads();
  for (int start = 0; start < nb; start += 256) {
    int i = start + threadIdx.x;
    int v = (i < nb) ? bsum[i] : 0;
    tmp[threadIdx.x] = v;
    __syncthreads();
    int acc = v;
    for (int off = 1; off < 256; off <<= 1) {
      int other = (threadIdx.x >= off) ? tmp[threadIdx.x - off] : 0;
      __syncthreads();
      acc += other;
      tmp[threadIdx.x] = acc;
      __syncthreads();
    }
    int c = carry;
    if (i < nb) bsum[i] = c + acc - v;
    __syncthreads();
    if (threadIdx.x == 255) carry = c + acc;
    __syncthreads();
  }
}

__global__ __launch_bounds__(256) void csr_finalize(int* __restrict__ rp,
                                                    const int* __restrict__ bsum,
                                                    int* __restrict__ cursor,
                                                    int n, int ne) {
  int i = blockIdx.x * 256 + threadIdx.x;
  if (i < n) {
    int v = rp[i] + bsum[i >> 8];
    rp[i] = v;
    cursor[i] = v;
  } else if (i == n) {
    rp[n] = ne;
  }
}

__global__ __launch_bounds__(256) void csr_scatter(const int* __restrict__ dst,
                                                   int* __restrict__ cursor,
                                                   int* __restrict__ ce, int n) {
  int e = blockIdx.x * 256 + threadIdx.x;
  if (e < n) {
    int slot = atomicAdd(&cursor[dst[e]], 1);
    ce[slot] = e;
  }
}

__global__ __launch_bounds__(256) void csr_sort(const int* __restrict__ rp,
                                                int* __restrict__ ce, int n) {
  int d = blockIdx.x * 256 + threadIdx.x;
  if (d >= n) return;
  int b = rp[d], e = rp[d + 1];
  for (int i = b + 1; i < e; i++) {
    int key = ce[i];
    int j = i - 1;
    while (j >= b && ce[j] > key) { ce[j + 1] = ce[j]; j--; }
    ce[j + 1] = key;
  }
}

// ---------------- attention ----------------
// slot-parallel: thread = (csr slot i, h).
// alpha[i,h] = k[src] . (A[h] @ q[dst]) * p[h] * scale   (written slot-ordered)
__global__ __launch_bounds__(256) void alpha_edge(
    const unsigned short* __restrict__ kbuf,
    const unsigned short* __restrict__ qbuf, const int* __restrict__ ce,
    const int* __restrict__ src, const int* __restrict__ dst,
    const float* __restrict__ A, const float* __restrict__ prel,
    float* __restrict__ alphaOut, int srcOff, int dstOff) {
  int t = blockIdx.x * 256 + threadIdx.x;
  if (t >= E * H) return;
  int i = t >> 2, h = t & 3;
  int e = ce[i];
  int s_ = src[e], d_ = dst[e];
  float qv[32];
  load32bf(qbuf + (size_t)(dstOff + d_) * HID + h * 32, qv);
  const float* Ar = A + h * D * D;
  float qA[32];
  #pragma unroll 4
  for (int d2 = 0; d2 < 32; d2++) {
    const float4* r4 = (const float4*)(Ar + d2 * 32);
    float a = 0.f;
    #pragma unroll
    for (int j = 0; j < 8; j++) {
      float4 w = r4[j];
      a += w.x * qv[j * 4] + w.y * qv[j * 4 + 1] + w.z * qv[j * 4 + 2] +
           w.w * qv[j * 4 + 3];
    }
    qA[d2] = a;
  }
  float kk[32];
  load32bf(kbuf + (size_t)(srcOff + s_) * HID + h * 32, kk);
  float a = 0.f;
  #pragma unroll
  for (int j = 0; j < 32; j++) a += qA[j] * kk[j];
  a *= prel[h] * SCALE;
  alphaOut[(size_t)i * H + h] = a;
}

// lane-parallel aggregation: 32-lane group per (dst, h); lane = output dim.
// phase1: wave-parallel max; phase2: per-edge coalesced v gather + den;
// then M transform via shfl broadcast. Deterministic (slot order).
__global__ __launch_bounds__(256) void agg_gather32(
    const unsigned short* __restrict__ vbuf, const int* __restrict__ rp0,
    const int* __restrict__ ce0, const int* __restrict__ src0,
    const float* __restrict__ M0, const float* __restrict__ alpha0,
    const int* __restrict__ rp1, const int* __restrict__ ce1,
    const int* __restrict__ src1, const float* __restrict__ M1,
    const float* __restrict__ alpha1, int net, int srcOff0, int srcOff1,
    int dstOff, int Ndst, unsigned short* __restrict__ agg) {
  int g = (blockIdx.x * 256 + threadIdx.x) >> 5;
  int lane = threadIdx.x & 31;
  if (g >= Ndst * H) return;
  int dl = g >> 2, h = g & 3;
  int b0 = rp0[dl], e0 = rp0[dl + 1];
  int b1 = 0, e1 = 0;
  if (net == 2) { b1 = rp1[dl]; e1 = rp1[dl + 1]; }
  // phase 1: lane-parallel max over this (dst,h)'s slots
  float mx = -INFINITY;
  for (int i = b0 + lane; i < e0; i += 32)
    mx = fmaxf(mx, alpha0[(size_t)i * H + h]);
  for (int i = b1 + lane; i < e1; i += 32)
    mx = fmaxf(mx, alpha1[(size_t)i * H + h]);
  #pragma unroll
  for (int m = 1; m < 32; m <<= 1) mx = fmaxf(mx, __shfl_xor(mx, m, 32));
  // phase 2: den + weighted v gather (lane=dim, coalesced) + M transform
  float den = 0.f, acc = 0.f;
  for (int s = 0; s < net; s++) {
    int b = s ? b1 : b0, en = s ? e1 : e0;
    if (b == en) continue;
    const int* ce = s ? ce1 : ce0;
    const int* src = s ? src1 : src0;
    const float* al = s ? alpha1 : alpha0;
    const float* Mm = (s ? M1 : M0) + h * D * D;
    int srcOff = s ? srcOff1 : srcOff0;
    float sv = 0.f;
    for (int i = b; i < en; i++) {
      float w = expf(al[(size_t)i * H + h] - mx);  // uniform across lanes
      den += w;
      int e = ce[i];
      float v = bf2f(vbuf[(size_t)(srcOff + src[e]) * HID + h * 32 + lane]);
      sv += w * v;
    }
    // acc[lane] += sum_d sv[d] * M[d][lane]  (M reads coalesced, L1-hot)
    #pragma unroll 8
    for (int d2 = 0; d2 < 32; d2++)
      acc += __shfl(sv, d2, 32) * Mm[d2 * 32 + lane];
  }
  float inv = 1.f / (den + 1e-16f);
  agg[(size_t)(dstOff + dl) * HID + h * 32 + lane] = f2bf(acc * inv);
}

__global__ __launch_bounds__(256) void head_kernel(
    const float* __restrict__ xs0, const float* __restrict__ w_head,
    const float* __restrict__ b_head, const float* __restrict__ basep,
    float* __restrict__ out, int Nrows) {
  int wid = (blockIdx.x * 256 + threadIdx.x) >> 6;
  int lane = threadIdx.x & 63;
  if (wid >= Nrows) return;
  size_t base = (size_t)wid * HID;
  float d = xs0[base + lane] * w_head[lane] +
            xs0[base + 64 + lane] * w_head[64 + lane];
  #pragma unroll
  for (int m = 1; m < 64; m <<= 1) d += __shfl_xor(d, m, 64);
  if (lane == 0) out[wid] = basep[0] + b_head[0] + d;
}

}  // namespace

extern "C" void kernel_launch(void* const* d_in, const int* in_sizes, int n_in,
                              void* d_out, int out_size, void* d_ws,
                              size_t ws_size, hipStream_t stream) {
  const float* x_a = (const float*)d_in[0];
  const float* x_w = (const float*)d_in[1];
  const float* x_o = (const float*)d_in[2];
  const float* W_in = (const float*)d_in[3];
  const float* b_in = (const float*)d_in[4];
  const float* W_kqv = (const float*)d_in[5];
  const float* b_kqv = (const float*)d_in[6];
  const float* a_rel = (const float*)d_in[7];
  const float* m_rel = (const float*)d_in[8];
  const float* p_rel = (const float*)d_in[9];
  const float* skip_p = (const float*)d_in[10];
  const float* W_o = (const float*)d_in[11];
  const float* b_o = (const float*)d_in[12];
  const float* ln_g = (const float*)d_in[13];
  const float* ln_b = (const float*)d_in[14];
  const float* w_head = (const float*)d_in[15];
  const float* b_head = (const float*)d_in[16];
  const float* basep = (const float*)d_in[17];
  const int* srcs[4] = {(const int*)d_in[18], (const int*)d_in[20],
                        (const int*)d_in[22], (const int*)d_in[24]};
  const int* dsts[4] = {(const int*)d_in[19], (const int*)d_in[21],
                        (const int*)d_in[23], (const int*)d_in[25]};
  const int OFF[4] = {0, NA, NA + NW, NTOT};
  const int NT[3] = {NA, NW, NO};
  const float* xin[3] = {x_a, x_w, x_o};

  // ---- workspace layout (~188 MB) ----
  const size_t SZ_XS = (size_t)NTOT * HID * 4;   // fp32 xs
  const size_t SZ_KV = (size_t)NTOT * HID * 2;   // bf16 k -> v
  const size_t SZ_QA = (size_t)NTOT * HID * 2;   // bf16 q -> agg
  const size_t SZ_AL = (size_t)4 * E * H * 4;    // fp32 slot-ordered alpha
  const int RP_TOT = 2 * (NA + 1) + (NW + 1) + (NO + 1);
  const size_t SZ_RP = ((size_t)RP_TOT * 4 + 63) & ~63ull;
  const size_t SZ_CE = (size_t)4 * E * 4;
  const size_t SZ_CU = ((size_t)(NA + 1) * 4 + 63) & ~63ull;
  const size_t SZ_BS = 512 * 4;
  const size_t need =
      SZ_XS + SZ_KV + SZ_QA + SZ_AL + SZ_RP + SZ_CE + 2 * SZ_CU + SZ_BS;
  if (ws_size < need) return;

  char* p = (char*)d_ws;
  float* xs = (float*)p;                     p += SZ_XS;
  unsigned short* kv = (unsigned short*)p;   p += SZ_KV;
  unsigned short* qagg = (unsigned short*)p; p += SZ_QA;
  float* alphaB = (float*)p;                 p += SZ_AL;
  int* rpAll = (int*)p;                      p += SZ_RP;
  int* ceAll = (int*)p;                      p += SZ_CE;
  int* cursor = (int*)p;                     p += SZ_CU;
  int* cnt = (int*)p;                        p += SZ_CU;
  int* bsum = (int*)p;

  const int rpOff[4] = {0, NA + 1, 2 * (NA + 1), 2 * (NA + 1) + NW + 1};
  const int NdstE[4] = {NA, NA, NW, NO};
  const int srcOffE[4] = {OFF[1], OFF[2], 0, 0};
  const int dstOffE[4] = {0, 0, OFF[1], OFF[2]};
  const int eb = (E + 255) / 256;
  const int ebh = (E * H + 255) / 256;

  // ---- CSR build (once; edges shared by both layers) ----
  for (int et = 0; et < 4; et++) {
    int nd = NdstE[et];
    int* rp = rpAll + rpOff[et];
    int* ce = ceAll + (size_t)et * E;
    hipMemsetAsync(cnt, 0, (size_t)nd * 4, stream);
    csr_hist<<<eb, 256, 0, stream>>>(dsts[et], cnt, E);
    int nb = (nd + 255) / 256;
    scan_block<<<nb, 256, 0, stream>>>(cnt, rp, bsum, nd);
    scan_bsums<<<1, 256, 0, stream>>>(bsum, nb);
    csr_finalize<<<(nd + 256) / 256 + 1, 256, 0, stream>>>(rp, bsum, cursor,
                                                           nd, E);
    csr_scatter<<<eb, 256, 0, stream>>>(dsts[et], cursor, ce, E);
    csr_sort<<<(nd + 255) / 256, 256, 0, stream>>>(rp, ce, nd);
  }

  // ---- input projection: xs[t] = relu(x @ W_in[t] + b_in[t]) ----
  for (int t = 0; t < 3; t++) {
    dim3 g((NT[t] + 63) / 64, 2);
    gemm_tiled<true, false><<<g, 256, 0, stream>>>(
        xin[t], W_in + (size_t)t * 64 * HID, b_in + t * HID,
        xs + (size_t)OFF[t] * HID, NT[t], 64, HID, HID);
  }

  for (int l = 0; l < 2; l++) {
    const size_t DD = (size_t)H * D * D;
    // k -> kv (bf16), q -> qagg (bf16)
    for (int t = 0; t < 3; t++) {
      const float* Wk = W_kqv + (size_t)(l * 3 + t) * HID * 3 * HID;
      const float* bk = b_kqv + (size_t)(l * 3 + t) * 3 * HID;
      dim3 g((NT[t] + 63) / 64, 2);
      gemm_tiled<false, true><<<g, 256, 0, stream>>>(
          xs + (size_t)OFF[t] * HID, Wk, bk, kv + (size_t)OFF[t] * HID, NT[t],
          HID, 3 * HID, HID);
      gemm_tiled<false, true><<<g, 256, 0, stream>>>(
          xs + (size_t)OFF[t] * HID, Wk + HID, bk + HID,
          qagg + (size_t)OFF[t] * HID, NT[t], HID, 3 * HID, HID);
    }
    // slot-parallel alpha, one launch per edge type
    const float* Al = a_rel + (size_t)l * 4 * DD;
    const float* Ml = m_rel + (size_t)l * 4 * DD;
    const float* Pl = p_rel + (size_t)l * 4 * H;
    for (int et = 0; et < 4; et++)
      alpha_edge<<<ebh, 256, 0, stream>>>(
          kv, qagg, ceAll + (size_t)et * E, srcs[et], dsts[et], Al + et * DD,
          Pl + et * H, alphaB + (size_t)et * E * H, srcOffE[et], dstOffE[et]);
    // v -> kv (bf16), overwriting k (dead after alpha)
    for (int t = 0; t < 3; t++) {
      const float* Wk = W_kqv + (size_t)(l * 3 + t) * HID * 3 * HID;
      const float* bk = b_kqv + (size_t)(l * 3 + t) * 3 * HID;
      dim3 g((NT[t] + 63) / 64, 2);
      gemm_tiled<false, true><<<g, 256, 0, stream>>>(
          xs + (size_t)OFF[t] * HID, Wk + 2 * HID, bk + 2 * HID,
          kv + (size_t)OFF[t] * HID, NT[t], HID, 3 * HID, HID);
    }
    // lane-parallel fused max/den + agg gather -> qagg (bf16), overwriting q
    agg_gather32<<<((size_t)NA * H * 32 + 255) / 256, 256, 0, stream>>>(
        kv, rpAll + rpOff[0], ceAll, srcs[0], Ml, alphaB, rpAll + rpOff[1],
        ceAll + E, srcs[1], Ml + DD, alphaB + (size_t)E * H, 2, srcOffE[0],
        srcOffE[1], 0, NA, qagg);
    agg_gather32<<<((size_t)NW * H * 32 + 255) / 256, 256, 0, stream>>>(
        kv, rpAll + rpOff[2], ceAll + 2 * (size_t)E, srcs[2], Ml + 2 * DD,
        alphaB + 2 * (size_t)E * H, nullptr, nullptr, nullptr, nullptr, nullptr,
        1, srcOffE[2], 0, OFF[1], NW, qagg);
    agg_gather32<<<((size_t)NO * H * 32 + 255) / 256, 256, 0, stream>>>(
        kv, rpAll + rpOff[3], ceAll + 3 * (size_t)E, srcs[3], Ml + 3 * DD,
        alphaB + 3 * (size_t)E * H, nullptr, nullptr, nullptr, nullptr, nullptr,
        1, srcOffE[3], 0, OFF[2], NO, qagg);
    // fused: xs = relu(LN(g*(gelu(agg) @ W_o + b_o) + (1-g)*xs))
    for (int t = 0; t < 3; t++) {
      int blocks = (NT[t] + 63) / 64;
      gemm_wo_ln<<<blocks, 256, 0, stream>>>(
          qagg + (size_t)OFF[t] * HID, W_o + (size_t)(l * 3 + t) * HID * HID,
          b_o + (size_t)(l * 3 + t) * HID, xs + (size_t)OFF[t] * HID,
          skip_p + l * 3 + t, ln_g + (size_t)(l * 3 + t) * HID,
          ln_b + (size_t)(l * 3 + t) * HID, NT[t]);
    }
  }
  head_kernel<<<(NA + 3) / 4, 256, 0, stream>>>(xs, w_head, b_head, basep,
                                                (float*)d_out, NA);
}

// Round 6
// 2977.487 us; speedup vs baseline: 1.5155x; 1.3588x over previous
//
#include <hip/hip_runtime.h>
#include <cstddef>
#include <cmath>

namespace {

constexpr int H = 4, D = 32, HID = 128;
constexpr int NA = 100000, NW = 20000, NO = 50000;
constexpr int NTOT = NA + NW + NO;
constexpr int E = 150000;
constexpr float SCALE = 0.17677669529663687f;  // 1/sqrt(32)

__device__ __forceinline__ float gelu_exact(float x) {
  return 0.5f * x * (1.f + erff(x * 0.7071067811865475f));
}

__device__ __forceinline__ unsigned short f2bf(float f) {  // RNE
  unsigned u = __float_as_uint(f);
  return (unsigned short)((u + 0x7FFF + ((u >> 16) & 1)) >> 16);
}
__device__ __forceinline__ float bf2f(unsigned short s) {
  return __uint_as_float(((unsigned)s) << 16);
}
__device__ __forceinline__ unsigned pack2(float lo, float hi) {
  return (unsigned)f2bf(lo) | ((unsigned)f2bf(hi) << 16);
}

// load 32 contiguous bf16 (as ushort) -> 32 floats; p must be 16B-aligned
__device__ __forceinline__ void load32bf(const unsigned short* p, float* out) {
  const uint4* u4 = (const uint4*)p;
  #pragma unroll
  for (int i = 0; i < 4; i++) {
    uint4 u = u4[i];
    unsigned w[4] = {u.x, u.y, u.z, u.w};
    #pragma unroll
    for (int j = 0; j < 4; j++) {
      out[i * 8 + j * 2 + 0] = __uint_as_float(w[j] << 16);
      out[i * 8 + j * 2 + 1] = __uint_as_float(w[j] & 0xFFFF0000u);
    }
  }
}

// ---------------- GEMM (fp32 compute) ----------------
template <bool RELU_OUT, bool OUT_BF16>
__global__ __launch_bounds__(256) void gemm_tiled(
    const float* __restrict__ A, const float* __restrict__ W,
    const float* __restrict__ bias, void* __restrict__ Cv,
    int M, int K, int ldw, int ldc) {
  __shared__ float As[32][68];
  __shared__ float Bs[32][68];
  const int tid = threadIdx.x;
  const int bm = blockIdx.x * 64;
  const int bn = blockIdx.y * 64;
  const int tx = tid & 15;
  const int ty = tid >> 4;
  float acc[4][4] = {};
  for (int kk = 0; kk < K; kk += 32) {
    #pragma unroll
    for (int i = 0; i < 8; i++) {
      int idx = tid + i * 256;
      int c = idx & 31, r = idx >> 5;
      int gr = bm + r;
      float v = 0.f;
      if (gr < M) v = A[(size_t)gr * K + kk + c];
      As[c][r] = v;
    }
    #pragma unroll
    for (int i = 0; i < 8; i++) {
      int idx = tid + i * 256;
      int c = idx & 63, r = idx >> 6;
      Bs[r][c] = W[(size_t)(kk + r) * ldw + bn + c];
    }
    __syncthreads();
    #pragma unroll
    for (int k = 0; k < 32; k++) {
      const float4 a4 = *(const float4*)&As[k][ty * 4];
      const float4 b4 = *(const float4*)&Bs[k][tx * 4];
      float av[4] = {a4.x, a4.y, a4.z, a4.w};
      float bv[4] = {b4.x, b4.y, b4.z, b4.w};
      #pragma unroll
      for (int i = 0; i < 4; i++)
        #pragma unroll
        for (int j = 0; j < 4; j++) acc[i][j] += av[i] * bv[j];
    }
    __syncthreads();
  }
  const float4 bb = *(const float4*)&bias[bn + tx * 4];
  float bv[4] = {bb.x, bb.y, bb.z, bb.w};
  #pragma unroll
  for (int i = 0; i < 4; i++) {
    int gr = bm + ty * 4 + i;
    if (gr >= M) continue;
    float o[4];
    #pragma unroll
    for (int j = 0; j < 4; j++) {
      o[j] = acc[i][j] + bv[j];
      if (RELU_OUT) o[j] = fmaxf(o[j], 0.f);
    }
    if (OUT_BF16) {
      ushort4 s;
      s.x = f2bf(o[0]); s.y = f2bf(o[1]); s.z = f2bf(o[2]); s.w = f2bf(o[3]);
      *(ushort4*)&((unsigned short*)Cv)[(size_t)gr * ldc + bn + tx * 4] = s;
    } else {
      float4 v;
      v.x = o[0]; v.y = o[1]; v.z = o[2]; v.w = o[3];
      *(float4*)&((float*)Cv)[(size_t)gr * ldc + bn + tx * 4] = v;
    }
  }
}

// fused: xs = relu(LN( g*(gelu(A_bf16) @ W_o + b_o) + (1-g)*xs ))
__global__ __launch_bounds__(256) void gemm_wo_ln(
    const unsigned short* __restrict__ A, const float* __restrict__ W,
    const float* __restrict__ bias, float* __restrict__ xs,
    const float* __restrict__ skip_p, const float* __restrict__ g_ln,
    const float* __restrict__ b_ln, int M) {
  __shared__ float As[32][68];
  __shared__ float Bs[32][132];
  const int tid = threadIdx.x;
  const int bm = blockIdx.x * 64;
  const int tx = tid & 15;   // 8 cols each
  const int ty = tid >> 4;   // 4 rows each
  float acc[4][8] = {};
  for (int kk = 0; kk < HID; kk += 32) {
    #pragma unroll
    for (int i = 0; i < 8; i++) {
      int idx = tid + i * 256;
      int c = idx & 31, r = idx >> 5;
      int gr = bm + r;
      float v = 0.f;
      if (gr < M) v = gelu_exact(bf2f(A[(size_t)gr * HID + kk + c]));
      As[c][r] = v;
    }
    #pragma unroll
    for (int i = 0; i < 16; i++) {
      int idx = tid + i * 256;
      int c = idx & 127, r = idx >> 7;
      Bs[r][c] = W[(size_t)(kk + r) * HID + c];
    }
    __syncthreads();
    #pragma unroll
    for (int k = 0; k < 32; k++) {
      const float4 a4 = *(const float4*)&As[k][ty * 4];
      const float4 b0 = *(const float4*)&Bs[k][tx * 8];
      const float4 b1 = *(const float4*)&Bs[k][tx * 8 + 4];
      float av[4] = {a4.x, a4.y, a4.z, a4.w};
      float bv[8] = {b0.x, b0.y, b0.z, b0.w, b1.x, b1.y, b1.z, b1.w};
      #pragma unroll
      for (int i = 0; i < 4; i++)
        #pragma unroll
        for (int j = 0; j < 8; j++) acc[i][j] += av[i] * bv[j];
    }
    __syncthreads();
  }
  const float g = 1.f / (1.f + expf(-skip_p[0]));
  float bb[8], gl[8], bl[8];
  #pragma unroll
  for (int j = 0; j < 8; j++) {
    bb[j] = bias[tx * 8 + j];
    gl[j] = g_ln[tx * 8 + j];
    bl[j] = b_ln[tx * 8 + j];
  }
  #pragma unroll
  for (int i = 0; i < 4; i++) {
    int gr = bm + ty * 4 + i;
    bool ok = gr < M;
    float xold[8] = {};
    if (ok) {
      const float4 x0 = *(const float4*)&xs[(size_t)gr * HID + tx * 8];
      const float4 x1 = *(const float4*)&xs[(size_t)gr * HID + tx * 8 + 4];
      xold[0] = x0.x; xold[1] = x0.y; xold[2] = x0.z; xold[3] = x0.w;
      xold[4] = x1.x; xold[5] = x1.y; xold[6] = x1.z; xold[7] = x1.w;
    }
    float v[8];
    float sum = 0.f, sq = 0.f;
    #pragma unroll
    for (int j = 0; j < 8; j++) {
      v[j] = g * (acc[i][j] + bb[j]) + (1.f - g) * xold[j];
      sum += v[j];
      sq += v[j] * v[j];
    }
    #pragma unroll
    for (int m = 1; m < 16; m <<= 1) {
      sum += __shfl_xor(sum, m, 64);
      sq += __shfl_xor(sq, m, 64);
    }
    float mu = sum * (1.f / 128.f);
    float var = sq * (1.f / 128.f) - mu * mu;
    float r = rsqrtf(var + 1e-5f);
    if (ok) {
      float y[8];
      #pragma unroll
      for (int j = 0; j < 8; j++)
        y[j] = fmaxf((v[j] - mu) * r * gl[j] + bl[j], 0.f);
      float4 o0, o1;
      o0.x = y[0]; o0.y = y[1]; o0.z = y[2]; o0.w = y[3];
      o1.x = y[4]; o1.y = y[5]; o1.z = y[6]; o1.w = y[7];
      *(float4*)&xs[(size_t)gr * HID + tx * 8] = o0;
      *(float4*)&xs[(size_t)gr * HID + tx * 8 + 4] = o1;
    }
  }
}

// ---------------- CSR build (deterministic) ----------------
__global__ __launch_bounds__(256) void csr_hist(const int* __restrict__ dst,
                                                int* __restrict__ cnt, int n) {
  int e = blockIdx.x * 256 + threadIdx.x;
  if (e < n) atomicAdd(&cnt[dst[e]], 1);
}

__global__ __launch_bounds__(256) void scan_block(const int* __restrict__ cnt,
                                                  int* __restrict__ excl,
                                                  int* __restrict__ bsum,
                                                  int n) {
  __shared__ int tmp[256];
  int i = blockIdx.x * 256 + threadIdx.x;
  int v = (i < n) ? cnt[i] : 0;
  tmp[threadIdx.x] = v;
  __syncthreads();
  int acc = v;
  for (int off = 1; off < 256; off <<= 1) {
    int other = (threadIdx.x >= off) ? tmp[threadIdx.x - off] : 0;
    __syncthreads();
    acc += other;
    tmp[threadIdx.x] = acc;
    __syncthreads();
  }
  if (i < n) excl[i] = acc - v;
  if (threadIdx.x == 255) bsum[blockIdx.x] = acc;
}

__global__ __launch_bounds__(256) void scan_bsums(int* __restrict__ bsum,
                                                  int nb) {
  __shared__ int tmp[256];
  __shared__ int carry;
  if (threadIdx.x == 0) carry = 0;
  __syncthreads();
  for (int start = 0; start < nb; start += 256) {
    int i = start + threadIdx.x;
    int v = (i < nb) ? bsum[i] : 0;
    tmp[threadIdx.x] = v;
    __syncthreads();
    int acc = v;
    for (int off = 1; off < 256; off <<= 1) {
      int other = (threadIdx.x >= off) ? tmp[threadIdx.x - off] : 0;
      __syncthreads();
      acc += other;
      tmp[threadIdx.x] = acc;
      __syncthreads();
    }
    int c = carry;
    if (i < nb) bsum[i] = c + acc - v;
    __syncthreads();
    if (threadIdx.x == 255) carry = c + acc;
    __syncthreads();
  }
}

__global__ __launch_bounds__(256) void csr_finalize(int* __restrict__ rp,
                                                    const int* __restrict__ bsum,
                                                    int* __restrict__ cursor,
                                                    int n, int ne) {
  int i = blockIdx.x * 256 + threadIdx.x;
  if (i < n) {
    int v = rp[i] + bsum[i >> 8];
    rp[i] = v;
    cursor[i] = v;
  } else if (i == n) {
    rp[n] = ne;
  }
}

__global__ __launch_bounds__(256) void csr_scatter(const int* __restrict__ dst,
                                                   int* __restrict__ cursor,
                                                   int* __restrict__ ce, int n) {
  int e = blockIdx.x * 256 + threadIdx.x;
  if (e < n) {
    int slot = atomicAdd(&cursor[dst[e]], 1);
    ce[slot] = e;
  }
}

__global__ __launch_bounds__(256) void csr_sort(const int* __restrict__ rp,
                                                int* __restrict__ ce, int n) {
  int d = blockIdx.x * 256 + threadIdx.x;
  if (d >= n) return;
  int b = rp[d], e = rp[d + 1];
  for (int i = b + 1; i < e; i++) {
    int key = ce[i];
    int j = i - 1;
    while (j >= b && ce[j] > key) { ce[j + 1] = ce[j]; j--; }
    ce[j + 1] = key;
  }
}

// slot-ordered src/dst id arrays (kills the ce->src/dst indirection)
__global__ __launch_bounds__(256) void build_sd(
    const int* __restrict__ ce, const int* __restrict__ s0,
    const int* __restrict__ s1, const int* __restrict__ s2,
    const int* __restrict__ s3, const int* __restrict__ d0,
    const int* __restrict__ d1, const int* __restrict__ d2,
    const int* __restrict__ d3, int* __restrict__ srcOf,
    int* __restrict__ dstOf) {
  int t = blockIdx.x * 256 + threadIdx.x;
  if (t >= 4 * E) return;
  int et = t / E;
  int e = ce[t];
  const int* sp = et == 0 ? s0 : et == 1 ? s1 : et == 2 ? s2 : s3;
  const int* dp = et == 0 ? d0 : et == 1 ? d1 : et == 2 ? d2 : d3;
  srcOf[t] = sp[e];
  dstOf[t] = dp[e];
}

// ---------------- attention ----------------
// per (src-node, h): ke[n,h,e] = sum_d k[n,h,d] * A[h,d,e]   (bf16 out)
__global__ __launch_bounds__(256) void krel(
    const unsigned short* __restrict__ kv, const float* __restrict__ A,
    unsigned short* __restrict__ ke, int srcOff, int Nsrc) {
  int t = blockIdx.x * 256 + threadIdx.x;
  if (t >= Nsrc * H) return;
  int n = t >> 2, h = t & 3;
  float kk[32];
  load32bf(kv + (size_t)(srcOff + n) * HID + h * 32, kk);
  const float* Ar = A + h * D * D;
  float o[32] = {};
  #pragma unroll 8
  for (int d2 = 0; d2 < 32; d2++) {
    float kd = kk[d2];
    const float4* row = (const float4*)(Ar + d2 * 32);
    #pragma unroll
    for (int j = 0; j < 8; j++) {
      float4 w = row[j];
      o[j * 4 + 0] += kd * w.x; o[j * 4 + 1] += kd * w.y;
      o[j * 4 + 2] += kd * w.z; o[j * 4 + 3] += kd * w.w;
    }
  }
  unsigned short* out = ke + (size_t)n * HID + h * 32;
  #pragma unroll
  for (int i = 0; i < 4; i++) {
    uint4 w;
    w.x = pack2(o[i * 8 + 0], o[i * 8 + 1]);
    w.y = pack2(o[i * 8 + 2], o[i * 8 + 3]);
    w.z = pack2(o[i * 8 + 4], o[i * 8 + 5]);
    w.w = pack2(o[i * 8 + 6], o[i * 8 + 7]);
    *(uint4*)(out + i * 8) = w;
  }
}

// per (slot,h): alpha = dot32(q[dst], ke[srcLocal]) * p * scale
__global__ __launch_bounds__(256) void alpha_slot(
    const unsigned short* __restrict__ ke,
    const unsigned short* __restrict__ qbuf, const int* __restrict__ srcOf,
    const int* __restrict__ dstOf, const float* __restrict__ prel,
    float* __restrict__ alphaOut, int dstOff) {
  int t = blockIdx.x * 256 + threadIdx.x;
  if (t >= E * H) return;
  int i = t >> 2, h = t & 3;
  int s_ = srcOf[i], d_ = dstOf[i];
  float qv[32], kk[32];
  load32bf(qbuf + (size_t)(dstOff + d_) * HID + h * 32, qv);
  load32bf(ke + (size_t)s_ * HID + h * 32, kk);
  float a = 0.f;
  #pragma unroll
  for (int j = 0; j < 32; j++) a += qv[j] * kk[j];
  alphaOut[(size_t)i * H + h] = a * prel[h] * SCALE;
}

// lane-parallel aggregation: 32-lane group per (dst, h); lane = output dim.
__global__ __launch_bounds__(256) void agg_gather32(
    const unsigned short* __restrict__ vbuf, const int* __restrict__ rp0,
    const int* __restrict__ srcOf0, const float* __restrict__ M0,
    const float* __restrict__ alpha0, const int* __restrict__ rp1,
    const int* __restrict__ srcOf1, const float* __restrict__ M1,
    const float* __restrict__ alpha1, int net, int srcOff0, int srcOff1,
    int dstOff, int Ndst, unsigned short* __restrict__ agg) {
  int g = (blockIdx.x * 256 + threadIdx.x) >> 5;
  int lane = threadIdx.x & 31;
  if (g >= Ndst * H) return;
  int dl = g >> 2, h = g & 3;
  int b0 = rp0[dl], e0 = rp0[dl + 1];
  int b1 = 0, e1 = 0;
  if (net == 2) { b1 = rp1[dl]; e1 = rp1[dl + 1]; }
  // phase 1: lane-parallel max over this (dst,h)'s slots
  float mx = -INFINITY;
  for (int i = b0 + lane; i < e0; i += 32)
    mx = fmaxf(mx, alpha0[(size_t)i * H + h]);
  for (int i = b1 + lane; i < e1; i += 32)
    mx = fmaxf(mx, alpha1[(size_t)i * H + h]);
  #pragma unroll
  for (int m = 1; m < 32; m <<= 1) mx = fmaxf(mx, __shfl_xor(mx, m, 32));
  // phase 2: den + weighted v gather (lane=dim, coalesced) + M transform
  float den = 0.f, acc = 0.f;
  for (int s = 0; s < net; s++) {
    int b = s ? b1 : b0, en = s ? e1 : e0;
    if (b == en) continue;
    const int* srcOf = s ? srcOf1 : srcOf0;
    const float* al = s ? alpha1 : alpha0;
    const float* Mm = (s ? M1 : M0) + h * D * D;
    int srcOff = s ? srcOff1 : srcOff0;
    float sv = 0.f;
    for (int i = b; i < en; i++) {
      float w = expf(al[(size_t)i * H + h] - mx);  // uniform across lanes
      den += w;
      float v = bf2f(vbuf[(size_t)(srcOff + srcOf[i]) * HID + h * 32 + lane]);
      sv += w * v;
    }
    #pragma unroll 8
    for (int d2 = 0; d2 < 32; d2++)
      acc += __shfl(sv, d2, 32) * Mm[d2 * 32 + lane];
  }
  float inv = 1.f / (den + 1e-16f);
  agg[(size_t)(dstOff + dl) * HID + h * 32 + lane] = f2bf(acc * inv);
}

__global__ __launch_bounds__(256) void head_kernel(
    const float* __restrict__ xs0, const float* __restrict__ w_head,
    const float* __restrict__ b_head, const float* __restrict__ basep,
    float* __restrict__ out, int Nrows) {
  int wid = (blockIdx.x * 256 + threadIdx.x) >> 6;
  int lane = threadIdx.x & 63;
  if (wid >= Nrows) return;
  size_t base = (size_t)wid * HID;
  float d = xs0[base + lane] * w_head[lane] +
            xs0[base + 64 + lane] * w_head[64 + lane];
  #pragma unroll
  for (int m = 1; m < 64; m <<= 1) d += __shfl_xor(d, m, 64);
  if (lane == 0) out[wid] = basep[0] + b_head[0] + d;
}

}  // namespace

extern "C" void kernel_launch(void* const* d_in, const int* in_sizes, int n_in,
                              void* d_out, int out_size, void* d_ws,
                              size_t ws_size, hipStream_t stream) {
  const float* x_a = (const float*)d_in[0];
  const float* x_w = (const float*)d_in[1];
  const float* x_o = (const float*)d_in[2];
  const float* W_in = (const float*)d_in[3];
  const float* b_in = (const float*)d_in[4];
  const float* W_kqv = (const float*)d_in[5];
  const float* b_kqv = (const float*)d_in[6];
  const float* a_rel = (const float*)d_in[7];
  const float* m_rel = (const float*)d_in[8];
  const float* p_rel = (const float*)d_in[9];
  const float* skip_p = (const float*)d_in[10];
  const float* W_o = (const float*)d_in[11];
  const float* b_o = (const float*)d_in[12];
  const float* ln_g = (const float*)d_in[13];
  const float* ln_b = (const float*)d_in[14];
  const float* w_head = (const float*)d_in[15];
  const float* b_head = (const float*)d_in[16];
  const float* basep = (const float*)d_in[17];
  const int* srcs[4] = {(const int*)d_in[18], (const int*)d_in[20],
                        (const int*)d_in[22], (const int*)d_in[24]};
  const int* dsts[4] = {(const int*)d_in[19], (const int*)d_in[21],
                        (const int*)d_in[23], (const int*)d_in[25]};
  const int OFF[4] = {0, NA, NA + NW, NTOT};
  const int NT[3] = {NA, NW, NO};
  const float* xin[3] = {x_a, x_w, x_o};

  // ---- workspace layout (~218 MB) ----
  const size_t SZ_XS = (size_t)NTOT * HID * 4;   // fp32 xs           87.0 MB
  const size_t SZ_KV = (size_t)NTOT * HID * 2;   // bf16 k -> v       43.5 MB
  const size_t SZ_QA = (size_t)NTOT * HID * 2;   // bf16 q -> agg     43.5 MB
  const size_t SZ_AL = (size_t)4 * E * H * 4;    // fp32 alpha         9.6 MB
  const size_t SZ_KE = (size_t)NA * HID * 2;     // bf16 k' (per-et)  25.6 MB
  const size_t SZ_SD = (size_t)4 * E * 4;        // srcOf / dstOf      2.4 MB x2
  const int RP_TOT = 2 * (NA + 1) + (NW + 1) + (NO + 1);
  const size_t SZ_RP = ((size_t)RP_TOT * 4 + 63) & ~63ull;
  const size_t SZ_CE = (size_t)4 * E * 4;
  const size_t SZ_CU = ((size_t)(NA + 1) * 4 + 63) & ~63ull;
  const size_t SZ_BS = 512 * 4;
  const size_t need = SZ_XS + SZ_KV + SZ_QA + SZ_AL + SZ_KE + 2 * SZ_SD +
                      SZ_RP + SZ_CE + 2 * SZ_CU + SZ_BS;
  if (ws_size < need) return;

  char* p = (char*)d_ws;
  float* xs = (float*)p;                     p += SZ_XS;
  unsigned short* kv = (unsigned short*)p;   p += SZ_KV;
  unsigned short* qagg = (unsigned short*)p; p += SZ_QA;
  float* alphaB = (float*)p;                 p += SZ_AL;
  unsigned short* keB = (unsigned short*)p;  p += SZ_KE;
  int* srcOf = (int*)p;                      p += SZ_SD;
  int* dstOf = (int*)p;                      p += SZ_SD;
  int* rpAll = (int*)p;                      p += SZ_RP;
  int* ceAll = (int*)p;                      p += SZ_CE;
  int* cursor = (int*)p;                     p += SZ_CU;
  int* cnt = (int*)p;                        p += SZ_CU;
  int* bsum = (int*)p;

  const int rpOff[4] = {0, NA + 1, 2 * (NA + 1), 2 * (NA + 1) + NW + 1};
  const int NdstE[4] = {NA, NA, NW, NO};
  const int NsrcE[4] = {NW, NO, NA, NA};
  const int srcOffE[4] = {OFF[1], OFF[2], 0, 0};
  const int dstOffE[4] = {0, 0, OFF[1], OFF[2]};
  const int eb = (E + 255) / 256;
  const int ebh = (E * H + 255) / 256;

  // ---- CSR build (once; edges shared by both layers) ----
  for (int et = 0; et < 4; et++) {
    int nd = NdstE[et];
    int* rp = rpAll + rpOff[et];
    int* ce = ceAll + (size_t)et * E;
    hipMemsetAsync(cnt, 0, (size_t)nd * 4, stream);
    csr_hist<<<eb, 256, 0, stream>>>(dsts[et], cnt, E);
    int nb = (nd + 255) / 256;
    scan_block<<<nb, 256, 0, stream>>>(cnt, rp, bsum, nd);
    scan_bsums<<<1, 256, 0, stream>>>(bsum, nb);
    csr_finalize<<<(nd + 256) / 256 + 1, 256, 0, stream>>>(rp, bsum, cursor,
                                                           nd, E);
    csr_scatter<<<eb, 256, 0, stream>>>(dsts[et], cursor, ce, E);
    csr_sort<<<(nd + 255) / 256, 256, 0, stream>>>(rp, ce, nd);
  }
  build_sd<<<(4 * E + 255) / 256, 256, 0, stream>>>(
      ceAll, srcs[0], srcs[1], srcs[2], srcs[3], dsts[0], dsts[1], dsts[2],
      dsts[3], srcOf, dstOf);

  // ---- input projection: xs[t] = relu(x @ W_in[t] + b_in[t]) ----
  for (int t = 0; t < 3; t++) {
    dim3 g((NT[t] + 63) / 64, 2);
    gemm_tiled<true, false><<<g, 256, 0, stream>>>(
        xin[t], W_in + (size_t)t * 64 * HID, b_in + t * HID,
        xs + (size_t)OFF[t] * HID, NT[t], 64, HID, HID);
  }

  for (int l = 0; l < 2; l++) {
    const size_t DD = (size_t)H * D * D;
    // k -> kv (bf16), q -> qagg (bf16)
    for (int t = 0; t < 3; t++) {
      const float* Wk = W_kqv + (size_t)(l * 3 + t) * HID * 3 * HID;
      const float* bk = b_kqv + (size_t)(l * 3 + t) * 3 * HID;
      dim3 g((NT[t] + 63) / 64, 2);
      gemm_tiled<false, true><<<g, 256, 0, stream>>>(
          xs + (size_t)OFF[t] * HID, Wk, bk, kv + (size_t)OFF[t] * HID, NT[t],
          HID, 3 * HID, HID);
      gemm_tiled<false, true><<<g, 256, 0, stream>>>(
          xs + (size_t)OFF[t] * HID, Wk + HID, bk + HID,
          qagg + (size_t)OFF[t] * HID, NT[t], HID, 3 * HID, HID);
    }
    // per-et: k' = k @ A_rel (once per src node), then slot-parallel alpha
    const float* Al = a_rel + (size_t)l * 4 * DD;
    const float* Ml = m_rel + (size_t)l * 4 * DD;
    const float* Pl = p_rel + (size_t)l * 4 * H;
    for (int et = 0; et < 4; et++) {
      krel<<<(NsrcE[et] * H + 255) / 256, 256, 0, stream>>>(
          kv, Al + et * DD, keB, srcOffE[et], NsrcE[et]);
      alpha_slot<<<ebh, 256, 0, stream>>>(
          keB, qagg, srcOf + (size_t)et * E, dstOf + (size_t)et * E,
          Pl + et * H, alphaB + (size_t)et * E * H, dstOffE[et]);
    }
    // v -> kv (bf16), overwriting k (dead after krel/alpha)
    for (int t = 0; t < 3; t++) {
      const float* Wk = W_kqv + (size_t)(l * 3 + t) * HID * 3 * HID;
      const float* bk = b_kqv + (size_t)(l * 3 + t) * 3 * HID;
      dim3 g((NT[t] + 63) / 64, 2);
      gemm_tiled<false, true><<<g, 256, 0, stream>>>(
          xs + (size_t)OFF[t] * HID, Wk + 2 * HID, bk + 2 * HID,
          kv + (size_t)OFF[t] * HID, NT[t], HID, 3 * HID, HID);
    }
    // lane-parallel fused max/den + agg gather -> qagg (bf16), overwriting q
    agg_gather32<<<((size_t)NA * H * 32 + 255) / 256, 256, 0, stream>>>(
        kv, rpAll + rpOff[0], srcOf, Ml, alphaB, rpAll + rpOff[1], srcOf + E,
        Ml + DD, alphaB + (size_t)E * H, 2, srcOffE[0], srcOffE[1], 0, NA,
        qagg);
    agg_gather32<<<((size_t)NW * H * 32 + 255) / 256, 256, 0, stream>>>(
        kv, rpAll + rpOff[2], srcOf + 2 * (size_t)E, Ml + 2 * DD,
        alphaB + 2 * (size_t)E * H, nullptr, nullptr, nullptr, nullptr, 1,
        srcOffE[2], 0, OFF[1], NW, qagg);
    agg_gather32<<<((size_t)NO * H * 32 + 255) / 256, 256, 0, stream>>>(
        kv, rpAll + rpOff[3], srcOf + 3 * (size_t)E, Ml + 3 * DD,
        alphaB + 3 * (size_t)E * H, nullptr, nullptr, nullptr, nullptr, 1,
        srcOffE[3], 0, OFF[2], NO, qagg);
    // fused: xs = relu(LN(g*(gelu(agg) @ W_o + b_o) + (1-g)*xs))
    for (int t = 0; t < 3; t++) {
      int blocks = (NT[t] + 63) / 64;
      gemm_wo_ln<<<blocks, 256, 0, stream>>>(
          qagg + (size_t)OFF[t] * HID, W_o + (size_t)(l * 3 + t) * HID * HID,
          b_o + (size_t)(l * 3 + t) * HID, xs + (size_t)OFF[t] * HID,
          skip_p + l * 3 + t, ln_g + (size_t)(l * 3 + t) * HID,
          ln_b + (size_t)(l * 3 + t) * HID, NT[t]);
    }
  }
  head_kernel<<<(NA + 3) / 4, 256, 0, stream>>>(xs, w_head, b_head, basep,
                                                (float*)d_out, NA);
}

// Round 7
// 2553.649 us; speedup vs baseline: 1.7670x; 1.1660x over previous
//
#include <hip/hip_runtime.h>
#include <cstddef>
#include <cmath>

namespace {

constexpr int H = 4, D = 32, HID = 128;
constexpr int NA = 100000, NW = 20000, NO = 50000;
constexpr int NTOT = NA + NW + NO;
constexpr int E = 150000;
constexpr float SCALE = 0.17677669529663687f;  // 1/sqrt(32)

__device__ __forceinline__ float gelu_exact(float x) {
  return 0.5f * x * (1.f + erff(x * 0.7071067811865475f));
}

__device__ __forceinline__ unsigned short f2bf(float f) {  // RNE
  unsigned u = __float_as_uint(f);
  return (unsigned short)((u + 0x7FFF + ((u >> 16) & 1)) >> 16);
}
__device__ __forceinline__ float bf2f(unsigned short s) {
  return __uint_as_float(((unsigned)s) << 16);
}

// ---------------- GEMM (fp32 compute) ----------------
template <bool RELU_OUT, bool OUT_BF16>
__global__ __launch_bounds__(256) void gemm_tiled(
    const float* __restrict__ A, const float* __restrict__ W,
    const float* __restrict__ bias, void* __restrict__ Cv,
    int M, int K, int ldw, int ldc) {
  __shared__ float As[32][68];
  __shared__ float Bs[32][68];
  const int tid = threadIdx.x;
  const int bm = blockIdx.x * 64;
  const int bn = blockIdx.y * 64;
  const int tx = tid & 15;
  const int ty = tid >> 4;
  float acc[4][4] = {};
  for (int kk = 0; kk < K; kk += 32) {
    #pragma unroll
    for (int i = 0; i < 8; i++) {
      int idx = tid + i * 256;
      int c = idx & 31, r = idx >> 5;
      int gr = bm + r;
      float v = 0.f;
      if (gr < M) v = A[(size_t)gr * K + kk + c];
      As[c][r] = v;
    }
    #pragma unroll
    for (int i = 0; i < 8; i++) {
      int idx = tid + i * 256;
      int c = idx & 63, r = idx >> 6;
      Bs[r][c] = W[(size_t)(kk + r) * ldw + bn + c];
    }
    __syncthreads();
    #pragma unroll
    for (int k = 0; k < 32; k++) {
      const float4 a4 = *(const float4*)&As[k][ty * 4];
      const float4 b4 = *(const float4*)&Bs[k][tx * 4];
      float av[4] = {a4.x, a4.y, a4.z, a4.w};
      float bv[4] = {b4.x, b4.y, b4.z, b4.w};
      #pragma unroll
      for (int i = 0; i < 4; i++)
        #pragma unroll
        for (int j = 0; j < 4; j++) acc[i][j] += av[i] * bv[j];
    }
    __syncthreads();
  }
  const float4 bb = *(const float4*)&bias[bn + tx * 4];
  float bv[4] = {bb.x, bb.y, bb.z, bb.w};
  #pragma unroll
  for (int i = 0; i < 4; i++) {
    int gr = bm + ty * 4 + i;
    if (gr >= M) continue;
    float o[4];
    #pragma unroll
    for (int j = 0; j < 4; j++) {
      o[j] = acc[i][j] + bv[j];
      if (RELU_OUT) o[j] = fmaxf(o[j], 0.f);
    }
    if (OUT_BF16) {
      ushort4 s;
      s.x = f2bf(o[0]); s.y = f2bf(o[1]); s.z = f2bf(o[2]); s.w = f2bf(o[3]);
      *(ushort4*)&((unsigned short*)Cv)[(size_t)gr * ldc + bn + tx * 4] = s;
    } else {
      float4 v;
      v.x = o[0]; v.y = o[1]; v.z = o[2]; v.w = o[3];
      *(float4*)&((float*)Cv)[(size_t)gr * ldc + bn + tx * 4] = v;
    }
  }
}

// fused: xs = relu(LN( g*(gelu(A_bf16) @ W_o + b_o) + (1-g)*xs ))
__global__ __launch_bounds__(256) void gemm_wo_ln(
    const unsigned short* __restrict__ A, const float* __restrict__ W,
    const float* __restrict__ bias, float* __restrict__ xs,
    const float* __restrict__ skip_p, const float* __restrict__ g_ln,
    const float* __restrict__ b_ln, int M) {
  __shared__ float As[32][68];
  __shared__ float Bs[32][132];
  const int tid = threadIdx.x;
  const int bm = blockIdx.x * 64;
  const int tx = tid & 15;   // 8 cols each
  const int ty = tid >> 4;   // 4 rows each
  float acc[4][8] = {};
  for (int kk = 0; kk < HID; kk += 32) {
    #pragma unroll
    for (int i = 0; i < 8; i++) {
      int idx = tid + i * 256;
      int c = idx & 31, r = idx >> 5;
      int gr = bm + r;
      float v = 0.f;
      if (gr < M) v = gelu_exact(bf2f(A[(size_t)gr * HID + kk + c]));
      As[c][r] = v;
    }
    #pragma unroll
    for (int i = 0; i < 16; i++) {
      int idx = tid + i * 256;
      int c = idx & 127, r = idx >> 7;
      Bs[r][c] = W[(size_t)(kk + r) * HID + c];
    }
    __syncthreads();
    #pragma unroll
    for (int k = 0; k < 32; k++) {
      const float4 a4 = *(const float4*)&As[k][ty * 4];
      const float4 b0 = *(const float4*)&Bs[k][tx * 8];
      const float4 b1 = *(const float4*)&Bs[k][tx * 8 + 4];
      float av[4] = {a4.x, a4.y, a4.z, a4.w};
      float bv[8] = {b0.x, b0.y, b0.z, b0.w, b1.x, b1.y, b1.z, b1.w};
      #pragma unroll
      for (int i = 0; i < 4; i++)
        #pragma unroll
        for (int j = 0; j < 8; j++) acc[i][j] += av[i] * bv[j];
    }
    __syncthreads();
  }
  const float g = 1.f / (1.f + expf(-skip_p[0]));
  float bb[8], gl[8], bl[8];
  #pragma unroll
  for (int j = 0; j < 8; j++) {
    bb[j] = bias[tx * 8 + j];
    gl[j] = g_ln[tx * 8 + j];
    bl[j] = b_ln[tx * 8 + j];
  }
  #pragma unroll
  for (int i = 0; i < 4; i++) {
    int gr = bm + ty * 4 + i;
    bool ok = gr < M;
    float xold[8] = {};
    if (ok) {
      const float4 x0 = *(const float4*)&xs[(size_t)gr * HID + tx * 8];
      const float4 x1 = *(const float4*)&xs[(size_t)gr * HID + tx * 8 + 4];
      xold[0] = x0.x; xold[1] = x0.y; xold[2] = x0.z; xold[3] = x0.w;
      xold[4] = x1.x; xold[5] = x1.y; xold[6] = x1.z; xold[7] = x1.w;
    }
    float v[8];
    float sum = 0.f, sq = 0.f;
    #pragma unroll
    for (int j = 0; j < 8; j++) {
      v[j] = g * (acc[i][j] + bb[j]) + (1.f - g) * xold[j];
      sum += v[j];
      sq += v[j] * v[j];
    }
    #pragma unroll
    for (int m = 1; m < 16; m <<= 1) {
      sum += __shfl_xor(sum, m, 64);
      sq += __shfl_xor(sq, m, 64);
    }
    float mu = sum * (1.f / 128.f);
    float var = sq * (1.f / 128.f) - mu * mu;
    float r = rsqrtf(var + 1e-5f);
    if (ok) {
      float y[8];
      #pragma unroll
      for (int j = 0; j < 8; j++)
        y[j] = fmaxf((v[j] - mu) * r * gl[j] + bl[j], 0.f);
      float4 o0, o1;
      o0.x = y[0]; o0.y = y[1]; o0.z = y[2]; o0.w = y[3];
      o1.x = y[4]; o1.y = y[5]; o1.z = y[6]; o1.w = y[7];
      *(float4*)&xs[(size_t)gr * HID + tx * 8] = o0;
      *(float4*)&xs[(size_t)gr * HID + tx * 8 + 4] = o1;
    }
  }
}

// ---------------- CSR build (deterministic) ----------------
__global__ __launch_bounds__(256) void csr_hist(const int* __restrict__ dst,
                                                int* __restrict__ cnt, int n) {
  int e = blockIdx.x * 256 + threadIdx.x;
  if (e < n) atomicAdd(&cnt[dst[e]], 1);
}

__global__ __launch_bounds__(256) void scan_block(const int* __restrict__ cnt,
                                                  int* __restrict__ excl,
                                                  int* __restrict__ bsum,
                                                  int n) {
  __shared__ int tmp[256];
  int i = blockIdx.x * 256 + threadIdx.x;
  int v = (i < n) ? cnt[i] : 0;
  tmp[threadIdx.x] = v;
  __syncthreads();
  int acc = v;
  for (int off = 1; off < 256; off <<= 1) {
    int other = (threadIdx.x >= off) ? tmp[threadIdx.x - off] : 0;
    __syncthreads();
    acc += other;
    tmp[threadIdx.x] = acc;
    __syncthreads();
  }
  if (i < n) excl[i] = acc - v;
  if (threadIdx.x == 255) bsum[blockIdx.x] = acc;
}

__global__ __launch_bounds__(256) void scan_bsums(int* __restrict__ bsum,
                                                  int nb) {
  __shared__ int tmp[256];
  __shared__ int carry;
  if (threadIdx.x == 0) carry = 0;
  __syncthreads();
  for (int start = 0; start < nb; start += 256) {
    int i = start + threadIdx.x;
    int v = (i < nb) ? bsum[i] : 0;
    tmp[threadIdx.x] = v;
    __syncthreads();
    int acc = v;
    for (int off = 1; off < 256; off <<= 1) {
      int other = (threadIdx.x >= off) ? tmp[threadIdx.x - off] : 0;
      __syncthreads();
      acc += other;
      tmp[threadIdx.x] = acc;
      __syncthreads();
    }
    int c = carry;
    if (i < nb) bsum[i] = c + acc - v;
    __syncthreads();
    if (threadIdx.x == 255) carry = c + acc;
    __syncthreads();
  }
}

__global__ __launch_bounds__(256) void csr_finalize(int* __restrict__ rp,
                                                    const int* __restrict__ bsum,
                                                    int* __restrict__ cursor,
                                                    int n, int ne) {
  int i = blockIdx.x * 256 + threadIdx.x;
  if (i < n) {
    int v = rp[i] + bsum[i >> 8];
    rp[i] = v;
    cursor[i] = v;
  } else if (i == n) {
    rp[n] = ne;
  }
}

__global__ __launch_bounds__(256) void csr_scatter(const int* __restrict__ dst,
                                                   int* __restrict__ cursor,
                                                   int* __restrict__ ce, int n) {
  int e = blockIdx.x * 256 + threadIdx.x;
  if (e < n) {
    int slot = atomicAdd(&cursor[dst[e]], 1);
    ce[slot] = e;
  }
}

__global__ __launch_bounds__(256) void csr_sort(const int* __restrict__ rp,
                                                int* __restrict__ ce, int n) {
  int d = blockIdx.x * 256 + threadIdx.x;
  if (d >= n) return;
  int b = rp[d], e = rp[d + 1];
  for (int i = b + 1; i < e; i++) {
    int key = ce[i];
    int j = i - 1;
    while (j >= b && ce[j] > key) { ce[j + 1] = ce[j]; j--; }
    ce[j + 1] = key;
  }
}

// slot-ordered src/dst id arrays (kills the ce->src/dst indirection)
__global__ __launch_bounds__(256) void build_sd(
    const int* __restrict__ ce, const int* __restrict__ s0,
    const int* __restrict__ s1, const int* __restrict__ s2,
    const int* __restrict__ s3, const int* __restrict__ d0,
    const int* __restrict__ d1, const int* __restrict__ d2,
    const int* __restrict__ d3, int* __restrict__ srcOf,
    int* __restrict__ dstOf) {
  int t = blockIdx.x * 256 + threadIdx.x;
  if (t >= 4 * E) return;
  int et = t / E;
  int e = ce[t];
  const int* sp = et == 0 ? s0 : et == 1 ? s1 : et == 2 ? s2 : s3;
  const int* dp = et == 0 ? d0 : et == 1 ? d1 : et == 2 ? d2 : d3;
  srcOf[t] = sp[e];
  dstOf[t] = dp[e];
}

// ---------------- attention ----------------
// lane-parallel krel: 32-lane group per (src-node, h); lane = output dim e.
// ke[n,h,e] = sum_d k[n,h,d] * A[h,d,e]  (same order as serial -> identical)
__global__ __launch_bounds__(256) void krel32(
    const unsigned short* __restrict__ kv, const float* __restrict__ A,
    unsigned short* __restrict__ ke, int srcOff, int Nsrc) {
  int g = (blockIdx.x * 256 + threadIdx.x) >> 5;
  int lane = threadIdx.x & 31;
  if (g >= Nsrc * H) return;
  int n = g >> 2, h = g & 3;
  float kd = bf2f(kv[(size_t)(srcOff + n) * HID + h * 32 + lane]);
  const float* Ar = A + h * D * D;
  float o = 0.f;
  #pragma unroll 8
  for (int d2 = 0; d2 < 32; d2++)
    o += __shfl(kd, d2, 32) * Ar[d2 * 32 + lane];
  ke[(size_t)n * HID + h * 32 + lane] = f2bf(o);
}

// lane-parallel alpha: 32-lane group per (slot, h); lane = dim.
// alpha = dot32(q[dst], ke[src]) * p * scale  (tree-reduced)
__global__ __launch_bounds__(256) void alpha32(
    const unsigned short* __restrict__ ke,
    const unsigned short* __restrict__ qbuf, const int* __restrict__ srcOf,
    const int* __restrict__ dstOf, const float* __restrict__ prel,
    float* __restrict__ alphaOut, int dstOff) {
  int g = (blockIdx.x * 256 + threadIdx.x) >> 5;
  int lane = threadIdx.x & 31;
  if (g >= E * H) return;
  int i = g >> 2, h = g & 3;
  int s_ = srcOf[i], d_ = dstOf[i];
  float pv = bf2f(qbuf[(size_t)(dstOff + d_) * HID + h * 32 + lane]) *
             bf2f(ke[(size_t)s_ * HID + h * 32 + lane]);
  #pragma unroll
  for (int m = 1; m < 32; m <<= 1) pv += __shfl_xor(pv, m, 32);
  if (lane == 0) alphaOut[(size_t)i * H + h] = pv * prel[h] * SCALE;
}

// lane-parallel aggregation: 32-lane group per (dst, h); lane = output dim.
__global__ __launch_bounds__(256) void agg_gather32(
    const unsigned short* __restrict__ vbuf, const int* __restrict__ rp0,
    const int* __restrict__ srcOf0, const float* __restrict__ M0,
    const float* __restrict__ alpha0, const int* __restrict__ rp1,
    const int* __restrict__ srcOf1, const float* __restrict__ M1,
    const float* __restrict__ alpha1, int net, int srcOff0, int srcOff1,
    int dstOff, int Ndst, unsigned short* __restrict__ agg) {
  int g = (blockIdx.x * 256 + threadIdx.x) >> 5;
  int lane = threadIdx.x & 31;
  if (g >= Ndst * H) return;
  int dl = g >> 2, h = g & 3;
  int b0 = rp0[dl], e0 = rp0[dl + 1];
  int b1 = 0, e1 = 0;
  if (net == 2) { b1 = rp1[dl]; e1 = rp1[dl + 1]; }
  // phase 1: lane-parallel max over this (dst,h)'s slots
  float mx = -INFINITY;
  for (int i = b0 + lane; i < e0; i += 32)
    mx = fmaxf(mx, alpha0[(size_t)i * H + h]);
  for (int i = b1 + lane; i < e1; i += 32)
    mx = fmaxf(mx, alpha1[(size_t)i * H + h]);
  #pragma unroll
  for (int m = 1; m < 32; m <<= 1) mx = fmaxf(mx, __shfl_xor(mx, m, 32));
  // phase 2: den + weighted v gather (lane=dim, coalesced) + M transform
  float den = 0.f, acc = 0.f;
  for (int s = 0; s < net; s++) {
    int b = s ? b1 : b0, en = s ? e1 : e0;
    if (b == en) continue;
    const int* srcOf = s ? srcOf1 : srcOf0;
    const float* al = s ? alpha1 : alpha0;
    const float* Mm = (s ? M1 : M0) + h * D * D;
    int srcOff = s ? srcOff1 : srcOff0;
    float sv = 0.f;
    for (int i = b; i < en; i++) {
      float w = expf(al[(size_t)i * H + h] - mx);  // uniform across lanes
      den += w;
      float v = bf2f(vbuf[(size_t)(srcOff + srcOf[i]) * HID + h * 32 + lane]);
      sv += w * v;
    }
    #pragma unroll 8
    for (int d2 = 0; d2 < 32; d2++)
      acc += __shfl(sv, d2, 32) * Mm[d2 * 32 + lane];
  }
  float inv = 1.f / (den + 1e-16f);
  agg[(size_t)(dstOff + dl) * HID + h * 32 + lane] = f2bf(acc * inv);
}

__global__ __launch_bounds__(256) void head_kernel(
    const float* __restrict__ xs0, const float* __restrict__ w_head,
    const float* __restrict__ b_head, const float* __restrict__ basep,
    float* __restrict__ out, int Nrows) {
  int wid = (blockIdx.x * 256 + threadIdx.x) >> 6;
  int lane = threadIdx.x & 63;
  if (wid >= Nrows) return;
  size_t base = (size_t)wid * HID;
  float d = xs0[base + lane] * w_head[lane] +
            xs0[base + 64 + lane] * w_head[64 + lane];
  #pragma unroll
  for (int m = 1; m < 64; m <<= 1) d += __shfl_xor(d, m, 64);
  if (lane == 0) out[wid] = basep[0] + b_head[0] + d;
}

}  // namespace

extern "C" void kernel_launch(void* const* d_in, const int* in_sizes, int n_in,
                              void* d_out, int out_size, void* d_ws,
                              size_t ws_size, hipStream_t stream) {
  const float* x_a = (const float*)d_in[0];
  const float* x_w = (const float*)d_in[1];
  const float* x_o = (const float*)d_in[2];
  const float* W_in = (const float*)d_in[3];
  const float* b_in = (const float*)d_in[4];
  const float* W_kqv = (const float*)d_in[5];
  const float* b_kqv = (const float*)d_in[6];
  const float* a_rel = (const float*)d_in[7];
  const float* m_rel = (const float*)d_in[8];
  const float* p_rel = (const float*)d_in[9];
  const float* skip_p = (const float*)d_in[10];
  const float* W_o = (const float*)d_in[11];
  const float* b_o = (const float*)d_in[12];
  const float* ln_g = (const float*)d_in[13];
  const float* ln_b = (const float*)d_in[14];
  const float* w_head = (const float*)d_in[15];
  const float* b_head = (const float*)d_in[16];
  const float* basep = (const float*)d_in[17];
  const int* srcs[4] = {(const int*)d_in[18], (const int*)d_in[20],
                        (const int*)d_in[22], (const int*)d_in[24]};
  const int* dsts[4] = {(const int*)d_in[19], (const int*)d_in[21],
                        (const int*)d_in[23], (const int*)d_in[25]};
  const int OFF[4] = {0, NA, NA + NW, NTOT};
  const int NT[3] = {NA, NW, NO};
  const float* xin[3] = {x_a, x_w, x_o};

  // ---- workspace layout (~218 MB) ----
  const size_t SZ_XS = (size_t)NTOT * HID * 4;   // fp32 xs           87.0 MB
  const size_t SZ_KV = (size_t)NTOT * HID * 2;   // bf16 k -> v       43.5 MB
  const size_t SZ_QA = (size_t)NTOT * HID * 2;   // bf16 q -> agg     43.5 MB
  const size_t SZ_AL = (size_t)4 * E * H * 4;    // fp32 alpha         9.6 MB
  const size_t SZ_KE = (size_t)NA * HID * 2;     // bf16 k' (per-et)  25.6 MB
  const size_t SZ_SD = (size_t)4 * E * 4;        // srcOf / dstOf      2.4 MB x2
  const int RP_TOT = 2 * (NA + 1) + (NW + 1) + (NO + 1);
  const size_t SZ_RP = ((size_t)RP_TOT * 4 + 63) & ~63ull;
  const size_t SZ_CE = (size_t)4 * E * 4;
  const size_t SZ_CU = ((size_t)(NA + 1) * 4 + 63) & ~63ull;
  const size_t SZ_BS = 512 * 4;
  const size_t need = SZ_XS + SZ_KV + SZ_QA + SZ_AL + SZ_KE + 2 * SZ_SD +
                      SZ_RP + SZ_CE + 2 * SZ_CU + SZ_BS;
  if (ws_size < need) return;

  char* p = (char*)d_ws;
  float* xs = (float*)p;                     p += SZ_XS;
  unsigned short* kv = (unsigned short*)p;   p += SZ_KV;
  unsigned short* qagg = (unsigned short*)p; p += SZ_QA;
  float* alphaB = (float*)p;                 p += SZ_AL;
  unsigned short* keB = (unsigned short*)p;  p += SZ_KE;
  int* srcOf = (int*)p;                      p += SZ_SD;
  int* dstOf = (int*)p;                      p += SZ_SD;
  int* rpAll = (int*)p;                      p += SZ_RP;
  int* ceAll = (int*)p;                      p += SZ_CE;
  int* cursor = (int*)p;                     p += SZ_CU;
  int* cnt = (int*)p;                        p += SZ_CU;
  int* bsum = (int*)p;

  const int rpOff[4] = {0, NA + 1, 2 * (NA + 1), 2 * (NA + 1) + NW + 1};
  const int NdstE[4] = {NA, NA, NW, NO};
  const int NsrcE[4] = {NW, NO, NA, NA};
  const int srcOffE[4] = {OFF[1], OFF[2], 0, 0};
  const int dstOffE[4] = {0, 0, OFF[1], OFF[2]};
  const int eb = (E + 255) / 256;

  // ---- CSR build (once; edges shared by both layers) ----
  for (int et = 0; et < 4; et++) {
    int nd = NdstE[et];
    int* rp = rpAll + rpOff[et];
    int* ce = ceAll + (size_t)et * E;
    hipMemsetAsync(cnt, 0, (size_t)nd * 4, stream);
    csr_hist<<<eb, 256, 0, stream>>>(dsts[et], cnt, E);
    int nb = (nd + 255) / 256;
    scan_block<<<nb, 256, 0, stream>>>(cnt, rp, bsum, nd);
    scan_bsums<<<1, 256, 0, stream>>>(bsum, nb);
    csr_finalize<<<(nd + 256) / 256 + 1, 256, 0, stream>>>(rp, bsum, cursor,
                                                           nd, E);
    csr_scatter<<<eb, 256, 0, stream>>>(dsts[et], cursor, ce, E);
    csr_sort<<<(nd + 255) / 256, 256, 0, stream>>>(rp, ce, nd);
  }
  build_sd<<<(4 * E + 255) / 256, 256, 0, stream>>>(
      ceAll, srcs[0], srcs[1], srcs[2], srcs[3], dsts[0], dsts[1], dsts[2],
      dsts[3], srcOf, dstOf);

  // ---- input projection: xs[t] = relu(x @ W_in[t] + b_in[t]) ----
  for (int t = 0; t < 3; t++) {
    dim3 g((NT[t] + 63) / 64, 2);
    gemm_tiled<true, false><<<g, 256, 0, stream>>>(
        xin[t], W_in + (size_t)t * 64 * HID, b_in + t * HID,
        xs + (size_t)OFF[t] * HID, NT[t], 64, HID, HID);
  }

  for (int l = 0; l < 2; l++) {
    const size_t DD = (size_t)H * D * D;
    // k -> kv (bf16), q -> qagg (bf16)
    for (int t = 0; t < 3; t++) {
      const float* Wk = W_kqv + (size_t)(l * 3 + t) * HID * 3 * HID;
      const float* bk = b_kqv + (size_t)(l * 3 + t) * 3 * HID;
      dim3 g((NT[t] + 63) / 64, 2);
      gemm_tiled<false, true><<<g, 256, 0, stream>>>(
          xs + (size_t)OFF[t] * HID, Wk, bk, kv + (size_t)OFF[t] * HID, NT[t],
          HID, 3 * HID, HID);
      gemm_tiled<false, true><<<g, 256, 0, stream>>>(
          xs + (size_t)OFF[t] * HID, Wk + HID, bk + HID,
          qagg + (size_t)OFF[t] * HID, NT[t], HID, 3 * HID, HID);
    }
    // per-et: k' = k @ A_rel (once per src node), then slot-parallel alpha
    const float* Al = a_rel + (size_t)l * 4 * DD;
    const float* Ml = m_rel + (size_t)l * 4 * DD;
    const float* Pl = p_rel + (size_t)l * 4 * H;
    for (int et = 0; et < 4; et++) {
      krel32<<<((size_t)NsrcE[et] * H * 32 + 255) / 256, 256, 0, stream>>>(
          kv, Al + et * DD, keB, srcOffE[et], NsrcE[et]);
      alpha32<<<((size_t)E * H * 32 + 255) / 256, 256, 0, stream>>>(
          keB, qagg, srcOf + (size_t)et * E, dstOf + (size_t)et * E,
          Pl + et * H, alphaB + (size_t)et * E * H, dstOffE[et]);
    }
    // v -> kv (bf16), overwriting k (dead after krel/alpha)
    for (int t = 0; t < 3; t++) {
      const float* Wk = W_kqv + (size_t)(l * 3 + t) * HID * 3 * HID;
      const float* bk = b_kqv + (size_t)(l * 3 + t) * 3 * HID;
      dim3 g((NT[t] + 63) / 64, 2);
      gemm_tiled<false, true><<<g, 256, 0, stream>>>(
          xs + (size_t)OFF[t] * HID, Wk + 2 * HID, bk + 2 * HID,
          kv + (size_t)OFF[t] * HID, NT[t], HID, 3 * HID, HID);
    }
    // lane-parallel fused max/den + agg gather -> qagg (bf16), overwriting q
    agg_gather32<<<((size_t)NA * H * 32 + 255) / 256, 256, 0, stream>>>(
        kv, rpAll + rpOff[0], srcOf, Ml, alphaB, rpAll + rpOff[1], srcOf + E,
        Ml + DD, alphaB + (size_t)E * H, 2, srcOffE[0], srcOffE[1], 0, NA,
        qagg);
    agg_gather32<<<((size_t)NW * H * 32 + 255) / 256, 256, 0, stream>>>(
        kv, rpAll + rpOff[2], srcOf + 2 * (size_t)E, Ml + 2 * DD,
        alphaB + 2 * (size_t)E * H, nullptr, nullptr, nullptr, nullptr, 1,
        srcOffE[2], 0, OFF[1], NW, qagg);
    agg_gather32<<<((size_t)NO * H * 32 + 255) / 256, 256, 0, stream>>>(
        kv, rpAll + rpOff[3], srcOf + 3 * (size_t)E, Ml + 3 * DD,
        alphaB + 3 * (size_t)E * H, nullptr, nullptr, nullptr, nullptr, 1,
        srcOffE[3], 0, OFF[2], NO, qagg);
    // fused: xs = relu(LN(g*(gelu(agg) @ W_o + b_o) + (1-g)*xs))
    for (int t = 0; t < 3; t++) {
      int blocks = (NT[t] + 63) / 64;
      gemm_wo_ln<<<blocks, 256, 0, stream>>>(
          qagg + (size_t)OFF[t] * HID, W_o + (size_t)(l * 3 + t) * HID * HID,
          b_o + (size_t)(l * 3 + t) * HID, xs + (size_t)OFF[t] * HID,
          skip_p + l * 3 + t, ln_g + (size_t)(l * 3 + t) * HID,
          ln_b + (size_t)(l * 3 + t) * HID, NT[t]);
    }
  }
  head_kernel<<<(NA + 3) / 4, 256, 0, stream>>>(xs, w_head, b_head, basep,
                                                (float*)d_out, NA);
}

// Round 8
// 1955.253 us; speedup vs baseline: 2.3078x; 1.3060x over previous
//
#include <hip/hip_runtime.h>
#include <cstddef>
#include <cmath>

namespace {

constexpr int H = 4, D = 32, HID = 128;
constexpr int NA = 100000, NW = 20000, NO = 50000;
constexpr int NTOT = NA + NW + NO;
constexpr int E = 150000;
constexpr float SCALE = 0.17677669529663687f;  // 1/sqrt(32)

typedef __attribute__((ext_vector_type(8))) short short8v;
typedef __attribute__((ext_vector_type(4))) float f32x4;

__device__ __forceinline__ float gelu_exact(float x) {
  return 0.5f * x * (1.f + erff(x * 0.7071067811865475f));
}

__device__ __forceinline__ unsigned short f2bf(float f) {  // RNE
  unsigned u = __float_as_uint(f);
  return (unsigned short)((u + 0x7FFF + ((u >> 16) & 1)) >> 16);
}
__device__ __forceinline__ float bf2f(unsigned short s) {
  return __uint_as_float(((unsigned)s) << 16);
}

// ---------------- MFMA GEMM: C_bf16 = act(A @ W_f32slice + bias) ----------
// tile 64x64, 256 thr = 4 waves, wave w owns rows [16w,16w+16). K = KSTEPS*32.
template <int KSTEPS, bool A_FP32, bool RELU_OUT>
__global__ __launch_bounds__(256) void gemm_mfma(
    const void* __restrict__ Av, const float* __restrict__ W,
    const float* __restrict__ bias, unsigned short* __restrict__ C,
    int M, int lda, int ldw, int ldc) {
  __shared__ unsigned short As[64][40];  // [m][k] bf16, 80B rows (16B-aligned)
  __shared__ unsigned short Bs[64][40];  // [n][k] bf16 (W transposed)
  const int tid = threadIdx.x;
  const int wv = tid >> 6;
  const int l = tid & 63;
  const int bm = blockIdx.x * 64, bn = blockIdx.y * 64;
  f32x4 acc[4] = {};
  const int srow = tid >> 2, sc8 = (tid & 3) * 8;  // A-staging coords
  for (int ks = 0; ks < KSTEPS; ks++) {
    const int kk = ks * 32;
    // stage A (64 rows x 32 k)
    {
      int gr = bm + srow;
      if (A_FP32) {
        unsigned short tmp[8] = {};
        if (gr < M) {
          const float* src = (const float*)Av + (size_t)gr * lda + kk + sc8;
          float4 f0 = *(const float4*)src;
          float4 f1 = *(const float4*)(src + 4);
          tmp[0] = f2bf(f0.x); tmp[1] = f2bf(f0.y);
          tmp[2] = f2bf(f0.z); tmp[3] = f2bf(f0.w);
          tmp[4] = f2bf(f1.x); tmp[5] = f2bf(f1.y);
          tmp[6] = f2bf(f1.z); tmp[7] = f2bf(f1.w);
        }
        *(uint4*)&As[srow][sc8] = *(const uint4*)tmp;
      } else {
        uint4 v = {0, 0, 0, 0};
        if (gr < M)
          v = *(const uint4*)((const unsigned short*)Av + (size_t)gr * lda +
                              kk + sc8);
        *(uint4*)&As[srow][sc8] = v;
      }
    }
    // stage B transposed: W[kk+r][bn+c] -> Bs[c][r]
    #pragma unroll
    for (int i = 0; i < 8; i++) {
      int idx = tid + i * 256;
      int r = idx >> 6, c = idx & 63;
      Bs[c][r] = f2bf(W[(size_t)(kk + r) * ldw + bn + c]);
    }
    __syncthreads();
    const int arow = wv * 16 + (l & 15);
    const int k8 = (l >> 4) * 8;
    short8v af = *(const short8v*)&As[arow][k8];
    #pragma unroll
    for (int n = 0; n < 4; n++) {
      short8v bf = *(const short8v*)&Bs[n * 16 + (l & 15)][k8];
      acc[n] = __builtin_amdgcn_mfma_f32_16x16x32_bf16(af, bf, acc[n], 0, 0, 0);
    }
    __syncthreads();
  }
  #pragma unroll
  for (int n = 0; n < 4; n++) {
    int col = bn + n * 16 + (l & 15);
    float bb = bias[col];
    #pragma unroll
    for (int j = 0; j < 4; j++) {
      int row = bm + wv * 16 + (l >> 4) * 4 + j;
      if (row < M) {
        float o = acc[n][j] + bb;
        if (RELU_OUT) o = fmaxf(o, 0.f);
        C[(size_t)row * ldc + col] = f2bf(o);
      }
    }
  }
}

// fused: xs = relu(LN( g*(gelu(A_bf16) @ W_o + b_o) + (1-g)*xs ))  [MFMA]
// tile 64x128 (full row per block), K=128.
__global__ __launch_bounds__(256) void wo_ln_mfma(
    const unsigned short* __restrict__ A, const float* __restrict__ W,
    const float* __restrict__ bias, unsigned short* __restrict__ xs,
    const float* __restrict__ skip_p, const float* __restrict__ g_ln,
    const float* __restrict__ b_ln, int M) {
  __shared__ unsigned short As[64][40];
  __shared__ unsigned short Bs[128][40];
  const int tid = threadIdx.x;
  const int wv = tid >> 6;
  const int l = tid & 63;
  const int bm = blockIdx.x * 64;
  f32x4 acc[8] = {};
  const int srow = tid >> 2, sc8 = (tid & 3) * 8;
  for (int ks = 0; ks < 4; ks++) {
    const int kk = ks * 32;
    {  // stage A with gelu
      int gr = bm + srow;
      uint4 v = {0, 0, 0, 0};
      if (gr < M)
        v = *(const uint4*)(A + (size_t)gr * HID + kk + sc8);
      unsigned w4[4] = {v.x, v.y, v.z, v.w};
      unsigned short tmp[8];
      #pragma unroll
      for (int j = 0; j < 4; j++) {
        tmp[j * 2 + 0] = f2bf(gelu_exact(bf2f((unsigned short)(w4[j] & 0xFFFF))));
        tmp[j * 2 + 1] = f2bf(gelu_exact(bf2f((unsigned short)(w4[j] >> 16))));
      }
      *(uint4*)&As[srow][sc8] = *(const uint4*)tmp;
    }
    #pragma unroll
    for (int i = 0; i < 16; i++) {
      int idx = tid + i * 256;
      int r = idx >> 7, c = idx & 127;
      Bs[c][r] = f2bf(W[(size_t)(kk + r) * HID + c]);
    }
    __syncthreads();
    const int arow = wv * 16 + (l & 15);
    const int k8 = (l >> 4) * 8;
    short8v af = *(const short8v*)&As[arow][k8];
    #pragma unroll
    for (int n = 0; n < 8; n++) {
      short8v bf = *(const short8v*)&Bs[n * 16 + (l & 15)][k8];
      acc[n] = __builtin_amdgcn_mfma_f32_16x16x32_bf16(af, bf, acc[n], 0, 0, 0);
    }
    __syncthreads();
  }
  const float g = 1.f / (1.f + expf(-skip_p[0]));
  float bb[8], gl[8], bl[8];
  #pragma unroll
  for (int n = 0; n < 8; n++) {
    int col = n * 16 + (l & 15);
    bb[n] = bias[col];
    gl[n] = g_ln[col];
    bl[n] = b_ln[col];
  }
  #pragma unroll
  for (int j = 0; j < 4; j++) {
    int row = bm + wv * 16 + (l >> 4) * 4 + j;
    bool ok = row < M;
    float vv[8], sum = 0.f, sq = 0.f;
    #pragma unroll
    for (int n = 0; n < 8; n++) {
      int col = n * 16 + (l & 15);
      float xo = ok ? bf2f(xs[(size_t)row * HID + col]) : 0.f;
      float val = g * (acc[n][j] + bb[n]) + (1.f - g) * xo;
      vv[n] = val;
      sum += val;
      sq += val * val;
    }
    #pragma unroll
    for (int m = 1; m < 16; m <<= 1) {
      sum += __shfl_xor(sum, m, 64);
      sq += __shfl_xor(sq, m, 64);
    }
    float mu = sum * (1.f / 128.f);
    float var = sq * (1.f / 128.f) - mu * mu;
    float r = rsqrtf(var + 1e-5f);
    if (ok) {
      #pragma unroll
      for (int n = 0; n < 8; n++) {
        float y = fmaxf((vv[n] - mu) * r * gl[n] + bl[n], 0.f);
        xs[(size_t)row * HID + n * 16 + (l & 15)] = f2bf(y);
      }
    }
  }
}

// ---------------- CSR build (deterministic) ----------------
__global__ __launch_bounds__(256) void csr_hist(const int* __restrict__ dst,
                                                int* __restrict__ cnt, int n) {
  int e = blockIdx.x * 256 + threadIdx.x;
  if (e < n) atomicAdd(&cnt[dst[e]], 1);
}

__global__ __launch_bounds__(256) void scan_block(const int* __restrict__ cnt,
                                                  int* __restrict__ excl,
                                                  int* __restrict__ bsum,
                                                  int n) {
  __shared__ int tmp[256];
  int i = blockIdx.x * 256 + threadIdx.x;
  int v = (i < n) ? cnt[i] : 0;
  tmp[threadIdx.x] = v;
  __syncthreads();
  int acc = v;
  for (int off = 1; off < 256; off <<= 1) {
    int other = (threadIdx.x >= off) ? tmp[threadIdx.x - off] : 0;
    __syncthreads();
    acc += other;
    tmp[threadIdx.x] = acc;
    __syncthreads();
  }
  if (i < n) excl[i] = acc - v;
  if (threadIdx.x == 255) bsum[blockIdx.x] = acc;
}

__global__ __launch_bounds__(256) void scan_bsums(int* __restrict__ bsum,
                                                  int nb) {
  __shared__ int tmp[256];
  __shared__ int carry;
  if (threadIdx.x == 0) carry = 0;
  __syncthreads();
  for (int start = 0; start < nb; start += 256) {
    int i = start + threadIdx.x;
    int v = (i < nb) ? bsum[i] : 0;
    tmp[threadIdx.x] = v;
    __syncthreads();
    int acc = v;
    for (int off = 1; off < 256; off <<= 1) {
      int other = (threadIdx.x >= off) ? tmp[threadIdx.x - off] : 0;
      __syncthreads();
      acc += other;
      tmp[threadIdx.x] = acc;
      __syncthreads();
    }
    int c = carry;
    if (i < nb) bsum[i] = c + acc - v;
    __syncthreads();
    if (threadIdx.x == 255) carry = c + acc;
    __syncthreads();
  }
}

__global__ __launch_bounds__(256) void csr_finalize(int* __restrict__ rp,
                                                    const int* __restrict__ bsum,
                                                    int* __restrict__ cursor,
                                                    int n, int ne) {
  int i = blockIdx.x * 256 + threadIdx.x;
  if (i < n) {
    int v = rp[i] + bsum[i >> 8];
    rp[i] = v;
    cursor[i] = v;
  } else if (i == n) {
    rp[n] = ne;
  }
}

__global__ __launch_bounds__(256) void csr_scatter(const int* __restrict__ dst,
                                                   int* __restrict__ cursor,
                                                   int* __restrict__ ce, int n) {
  int e = blockIdx.x * 256 + threadIdx.x;
  if (e < n) {
    int slot = atomicAdd(&cursor[dst[e]], 1);
    ce[slot] = e;
  }
}

__global__ __launch_bounds__(256) void csr_sort(const int* __restrict__ rp,
                                                int* __restrict__ ce, int n) {
  int d = blockIdx.x * 256 + threadIdx.x;
  if (d >= n) return;
  int b = rp[d], e = rp[d + 1];
  for (int i = b + 1; i < e; i++) {
    int key = ce[i];
    int j = i - 1;
    while (j >= b && ce[j] > key) { ce[j + 1] = ce[j]; j--; }
    ce[j + 1] = key;
  }
}

__global__ __launch_bounds__(256) void build_sd(
    const int* __restrict__ ce, const int* __restrict__ s0,
    const int* __restrict__ s1, const int* __restrict__ s2,
    const int* __restrict__ s3, const int* __restrict__ d0,
    const int* __restrict__ d1, const int* __restrict__ d2,
    const int* __restrict__ d3, int* __restrict__ srcOf,
    int* __restrict__ dstOf) {
  int t = blockIdx.x * 256 + threadIdx.x;
  if (t >= 4 * E) return;
  int et = t / E;
  int e = ce[t];
  const int* sp = et == 0 ? s0 : et == 1 ? s1 : et == 2 ? s2 : s3;
  const int* dp = et == 0 ? d0 : et == 1 ? d1 : et == 2 ? d2 : d3;
  srcOf[t] = sp[e];
  dstOf[t] = dp[e];
}

// ---------------- attention ----------------
__global__ __launch_bounds__(256) void krel32(
    const unsigned short* __restrict__ kv, const float* __restrict__ A,
    unsigned short* __restrict__ ke, int srcOff, int Nsrc) {
  int g = (blockIdx.x * 256 + threadIdx.x) >> 5;
  int lane = threadIdx.x & 31;
  if (g >= Nsrc * H) return;
  int n = g >> 2, h = g & 3;
  float kd = bf2f(kv[(size_t)(srcOff + n) * HID + h * 32 + lane]);
  const float* Ar = A + h * D * D;
  float o = 0.f;
  #pragma unroll 8
  for (int d2 = 0; d2 < 32; d2++)
    o += __shfl(kd, d2, 32) * Ar[d2 * 32 + lane];
  ke[(size_t)n * HID + h * 32 + lane] = f2bf(o);
}

__global__ __launch_bounds__(256) void alpha32(
    const unsigned short* __restrict__ ke,
    const unsigned short* __restrict__ qbuf, const int* __restrict__ srcOf,
    const int* __restrict__ dstOf, const float* __restrict__ prel,
    float* __restrict__ alphaOut, int dstOff) {
  int g = (blockIdx.x * 256 + threadIdx.x) >> 5;
  int lane = threadIdx.x & 31;
  if (g >= E * H) return;
  int i = g >> 2, h = g & 3;
  int s_ = srcOf[i], d_ = dstOf[i];
  float pv = bf2f(qbuf[(size_t)(dstOff + d_) * HID + h * 32 + lane]) *
             bf2f(ke[(size_t)s_ * HID + h * 32 + lane]);
  #pragma unroll
  for (int m = 1; m < 32; m <<= 1) pv += __shfl_xor(pv, m, 32);
  if (lane == 0) alphaOut[(size_t)i * H + h] = pv * prel[h] * SCALE;
}

__global__ __launch_bounds__(256) void agg_gather32(
    const unsigned short* __restrict__ vbuf, const int* __restrict__ rp0,
    const int* __restrict__ srcOf0, const float* __restrict__ M0,
    const float* __restrict__ alpha0, const int* __restrict__ rp1,
    const int* __restrict__ srcOf1, const float* __restrict__ M1,
    const float* __restrict__ alpha1, int net, int srcOff0, int srcOff1,
    int dstOff, int Ndst, unsigned short* __restrict__ agg) {
  int g = (blockIdx.x * 256 + threadIdx.x) >> 5;
  int lane = threadIdx.x & 31;
  if (g >= Ndst * H) return;
  int dl = g >> 2, h = g & 3;
  int b0 = rp0[dl], e0 = rp0[dl + 1];
  int b1 = 0, e1 = 0;
  if (net == 2) { b1 = rp1[dl]; e1 = rp1[dl + 1]; }
  float mx = -INFINITY;
  for (int i = b0 + lane; i < e0; i += 32)
    mx = fmaxf(mx, alpha0[(size_t)i * H + h]);
  for (int i = b1 + lane; i < e1; i += 32)
    mx = fmaxf(mx, alpha1[(size_t)i * H + h]);
  #pragma unroll
  for (int m = 1; m < 32; m <<= 1) mx = fmaxf(mx, __shfl_xor(mx, m, 32));
  float den = 0.f, acc = 0.f;
  for (int s = 0; s < net; s++) {
    int b = s ? b1 : b0, en = s ? e1 : e0;
    if (b == en) continue;
    const int* srcOf = s ? srcOf1 : srcOf0;
    const float* al = s ? alpha1 : alpha0;
    const float* Mm = (s ? M1 : M0) + h * D * D;
    int srcOff = s ? srcOff1 : srcOff0;
    float sv = 0.f;
    for (int i = b; i < en; i++) {
      float w = expf(al[(size_t)i * H + h] - mx);
      den += w;
      float v = bf2f(vbuf[(size_t)(srcOff + srcOf[i]) * HID + h * 32 + lane]);
      sv += w * v;
    }
    #pragma unroll 8
    for (int d2 = 0; d2 < 32; d2++)
      acc += __shfl(sv, d2, 32) * Mm[d2 * 32 + lane];
  }
  float inv = 1.f / (den + 1e-16f);
  agg[(size_t)(dstOff + dl) * HID + h * 32 + lane] = f2bf(acc * inv);
}

__global__ __launch_bounds__(256) void head_kernel(
    const unsigned short* __restrict__ xs0, const float* __restrict__ w_head,
    const float* __restrict__ b_head, const float* __restrict__ basep,
    float* __restrict__ out, int Nrows) {
  int wid = (blockIdx.x * 256 + threadIdx.x) >> 6;
  int lane = threadIdx.x & 63;
  if (wid >= Nrows) return;
  size_t base = (size_t)wid * HID;
  float d = bf2f(xs0[base + lane]) * w_head[lane] +
            bf2f(xs0[base + 64 + lane]) * w_head[64 + lane];
  #pragma unroll
  for (int m = 1; m < 64; m <<= 1) d += __shfl_xor(d, m, 64);
  if (lane == 0) out[wid] = basep[0] + b_head[0] + d;
}

}  // namespace

extern "C" void kernel_launch(void* const* d_in, const int* in_sizes, int n_in,
                              void* d_out, int out_size, void* d_ws,
                              size_t ws_size, hipStream_t stream) {
  const float* x_a = (const float*)d_in[0];
  const float* x_w = (const float*)d_in[1];
  const float* x_o = (const float*)d_in[2];
  const float* W_in = (const float*)d_in[3];
  const float* b_in = (const float*)d_in[4];
  const float* W_kqv = (const float*)d_in[5];
  const float* b_kqv = (const float*)d_in[6];
  const float* a_rel = (const float*)d_in[7];
  const float* m_rel = (const float*)d_in[8];
  const float* p_rel = (const float*)d_in[9];
  const float* skip_p = (const float*)d_in[10];
  const float* W_o = (const float*)d_in[11];
  const float* b_o = (const float*)d_in[12];
  const float* ln_g = (const float*)d_in[13];
  const float* ln_b = (const float*)d_in[14];
  const float* w_head = (const float*)d_in[15];
  const float* b_head = (const float*)d_in[16];
  const float* basep = (const float*)d_in[17];
  const int* srcs[4] = {(const int*)d_in[18], (const int*)d_in[20],
                        (const int*)d_in[22], (const int*)d_in[24]};
  const int* dsts[4] = {(const int*)d_in[19], (const int*)d_in[21],
                        (const int*)d_in[23], (const int*)d_in[25]};
  const int OFF[4] = {0, NA, NA + NW, NTOT};
  const int NT[3] = {NA, NW, NO};
  const float* xin[3] = {x_a, x_w, x_o};

  // ---- workspace layout (~175 MB) ----
  const size_t SZ_XS = (size_t)NTOT * HID * 2;   // bf16 xs           43.5 MB
  const size_t SZ_KV = (size_t)NTOT * HID * 2;   // bf16 k -> v       43.5 MB
  const size_t SZ_QA = (size_t)NTOT * HID * 2;   // bf16 q -> agg     43.5 MB
  const size_t SZ_AL = (size_t)4 * E * H * 4;    // fp32 alpha         9.6 MB
  const size_t SZ_KE = (size_t)NA * HID * 2;     // bf16 k' (per-et)  25.6 MB
  const size_t SZ_SD = (size_t)4 * E * 4;        // srcOf / dstOf
  const int RP_TOT = 2 * (NA + 1) + (NW + 1) + (NO + 1);
  const size_t SZ_RP = ((size_t)RP_TOT * 4 + 63) & ~63ull;
  const size_t SZ_CE = (size_t)4 * E * 4;
  const size_t SZ_CU = ((size_t)(NA + 1) * 4 + 63) & ~63ull;
  const size_t SZ_BS = 512 * 4;
  const size_t need = SZ_XS + SZ_KV + SZ_QA + SZ_AL + SZ_KE + 2 * SZ_SD +
                      SZ_RP + SZ_CE + 2 * SZ_CU + SZ_BS;
  if (ws_size < need) return;

  char* p = (char*)d_ws;
  unsigned short* xs = (unsigned short*)p;   p += SZ_XS;
  unsigned short* kv = (unsigned short*)p;   p += SZ_KV;
  unsigned short* qagg = (unsigned short*)p; p += SZ_QA;
  float* alphaB = (float*)p;                 p += SZ_AL;
  unsigned short* keB = (unsigned short*)p;  p += SZ_KE;
  int* srcOf = (int*)p;                      p += SZ_SD;
  int* dstOf = (int*)p;                      p += SZ_SD;
  int* rpAll = (int*)p;                      p += SZ_RP;
  int* ceAll = (int*)p;                      p += SZ_CE;
  int* cursor = (int*)p;                     p += SZ_CU;
  int* cnt = (int*)p;                        p += SZ_CU;
  int* bsum = (int*)p;

  const int rpOff[4] = {0, NA + 1, 2 * (NA + 1), 2 * (NA + 1) + NW + 1};
  const int NdstE[4] = {NA, NA, NW, NO};
  const int NsrcE[4] = {NW, NO, NA, NA};
  const int srcOffE[4] = {OFF[1], OFF[2], 0, 0};
  const int dstOffE[4] = {0, 0, OFF[1], OFF[2]};
  const int eb = (E + 255) / 256;

  // ---- CSR build (once; edges shared by both layers) ----
  for (int et = 0; et < 4; et++) {
    int nd = NdstE[et];
    int* rp = rpAll + rpOff[et];
    int* ce = ceAll + (size_t)et * E;
    hipMemsetAsync(cnt, 0, (size_t)nd * 4, stream);
    csr_hist<<<eb, 256, 0, stream>>>(dsts[et], cnt, E);
    int nb = (nd + 255) / 256;
    scan_block<<<nb, 256, 0, stream>>>(cnt, rp, bsum, nd);
    scan_bsums<<<1, 256, 0, stream>>>(bsum, nb);
    csr_finalize<<<(nd + 256) / 256 + 1, 256, 0, stream>>>(rp, bsum, cursor,
                                                           nd, E);
    csr_scatter<<<eb, 256, 0, stream>>>(dsts[et], cursor, ce, E);
    csr_sort<<<(nd + 255) / 256, 256, 0, stream>>>(rp, ce, nd);
  }
  build_sd<<<(4 * E + 255) / 256, 256, 0, stream>>>(
      ceAll, srcs[0], srcs[1], srcs[2], srcs[3], dsts[0], dsts[1], dsts[2],
      dsts[3], srcOf, dstOf);

  // ---- input projection: xs[t] = relu(x @ W_in[t] + b_in[t]) [MFMA] ----
  for (int t = 0; t < 3; t++) {
    dim3 g((NT[t] + 63) / 64, 2);
    gemm_mfma<2, true, true><<<g, 256, 0, stream>>>(
        xin[t], W_in + (size_t)t * 64 * HID, b_in + t * HID,
        xs + (size_t)OFF[t] * HID, NT[t], 64, HID, HID);
  }

  for (int l = 0; l < 2; l++) {
    const size_t DD = (size_t)H * D * D;
    // k -> kv, q -> qagg  [MFMA]
    for (int t = 0; t < 3; t++) {
      const float* Wk = W_kqv + (size_t)(l * 3 + t) * HID * 3 * HID;
      const float* bk = b_kqv + (size_t)(l * 3 + t) * 3 * HID;
      dim3 g((NT[t] + 63) / 64, 2);
      gemm_mfma<4, false, false><<<g, 256, 0, stream>>>(
          xs + (size_t)OFF[t] * HID, Wk, bk, kv + (size_t)OFF[t] * HID, NT[t],
          HID, 3 * HID, HID);
      gemm_mfma<4, false, false><<<g, 256, 0, stream>>>(
          xs + (size_t)OFF[t] * HID, Wk + HID, bk + HID,
          qagg + (size_t)OFF[t] * HID, NT[t], HID, 3 * HID, HID);
    }
    const float* Al = a_rel + (size_t)l * 4 * DD;
    const float* Ml = m_rel + (size_t)l * 4 * DD;
    const float* Pl = p_rel + (size_t)l * 4 * H;
    for (int et = 0; et < 4; et++) {
      krel32<<<((size_t)NsrcE[et] * H * 32 + 255) / 256, 256, 0, stream>>>(
          kv, Al + et * DD, keB, srcOffE[et], NsrcE[et]);
      alpha32<<<((size_t)E * H * 32 + 255) / 256, 256, 0, stream>>>(
          keB, qagg, srcOf + (size_t)et * E, dstOf + (size_t)et * E,
          Pl + et * H, alphaB + (size_t)et * E * H, dstOffE[et]);
    }
    // v -> kv (overwriting k) [MFMA]
    for (int t = 0; t < 3; t++) {
      const float* Wk = W_kqv + (size_t)(l * 3 + t) * HID * 3 * HID;
      const float* bk = b_kqv + (size_t)(l * 3 + t) * 3 * HID;
      dim3 g((NT[t] + 63) / 64, 2);
      gemm_mfma<4, false, false><<<g, 256, 0, stream>>>(
          xs + (size_t)OFF[t] * HID, Wk + 2 * HID, bk + 2 * HID,
          kv + (size_t)OFF[t] * HID, NT[t], HID, 3 * HID, HID);
    }
    // lane-parallel fused max/den + agg gather -> qagg (overwriting q)
    agg_gather32<<<((size_t)NA * H * 32 + 255) / 256, 256, 0, stream>>>(
        kv, rpAll + rpOff[0], srcOf, Ml, alphaB, rpAll + rpOff[1], srcOf + E,
        Ml + DD, alphaB + (size_t)E * H, 2, srcOffE[0], srcOffE[1], 0, NA,
        qagg);
    agg_gather32<<<((size_t)NW * H * 32 + 255) / 256, 256, 0, stream>>>(
        kv, rpAll + rpOff[2], srcOf + 2 * (size_t)E, Ml + 2 * DD,
        alphaB + 2 * (size_t)E * H, nullptr, nullptr, nullptr, nullptr, 1,
        srcOffE[2], 0, OFF[1], NW, qagg);
    agg_gather32<<<((size_t)NO * H * 32 + 255) / 256, 256, 0, stream>>>(
        kv, rpAll + rpOff[3], srcOf + 3 * (size_t)E, Ml + 3 * DD,
        alphaB + 3 * (size_t)E * H, nullptr, nullptr, nullptr, nullptr, 1,
        srcOffE[3], 0, OFF[2], NO, qagg);
    // fused: xs = relu(LN(g*(gelu(agg) @ W_o + b_o) + (1-g)*xs)) [MFMA]
    for (int t = 0; t < 3; t++) {
      int blocks = (NT[t] + 63) / 64;
      wo_ln_mfma<<<blocks, 256, 0, stream>>>(
          qagg + (size_t)OFF[t] * HID, W_o + (size_t)(l * 3 + t) * HID * HID,
          b_o + (size_t)(l * 3 + t) * HID, xs + (size_t)OFF[t] * HID,
          skip_p + l * 3 + t, ln_g + (size_t)(l * 3 + t) * HID,
          ln_b + (size_t)(l * 3 + t) * HID, NT[t]);
    }
  }
  head_kernel<<<(NA + 3) / 4, 256, 0, stream>>>(xs, w_head, b_head, basep,
                                                (float*)d_out, NA);
}